// Round 9
// baseline (353.280 us; speedup 1.0000x reference)
//
#include <hip/hip_runtime.h>
#include <hip/hip_bf16.h>

#define N_NODES 100000
#define N_EDGES 1600000
#define FDIM 128
#define NCLS 40
#define NCLS_PAD 48

#define NBINS ((N_NODES + 255) / 256)        // 391 buckets of 256 nodes
#define NBLKB 128                            // partition blocks
#define CHUNKB (N_EDGES / NBLKB)             // 12500 edges per block
#define SCANTOT (NBINS * NBLKB)              // 50048
#define SCANB_NB ((SCANTOT + 1023) / 1024)   // 49

#define LPAD 136                             // LDS row pad: 272B = 68 words -> bank stride 4

typedef __attribute__((ext_vector_type(8))) short short8;
typedef __attribute__((ext_vector_type(4))) float f32x4;

__device__ __forceinline__ float bf2f(unsigned short u) {
    union { unsigned int i; float f; } v; v.i = ((unsigned int)u) << 16; return v.f;
}
__device__ __forceinline__ unsigned short f2bf(float f) {
    __hip_bfloat16 h = __float2bfloat16(f);
    return *reinterpret_cast<unsigned short*>(&h);
}

// ---------------- fp32 -> bf16 bulk convert (vectorized) ----------------
__global__ void k_cvt_bf16(const float4* __restrict__ in, ushort4* __restrict__ out, int n4) {
    int i = blockIdx.x * blockDim.x + threadIdx.x;
    if (i >= n4) return;
    float4 v = in[i];
    ushort4 o;
    o.x = f2bf(v.x); o.y = f2bf(v.y); o.z = f2bf(v.z); o.w = f2bf(v.w);
    out[i] = o;
}

// ---------------- radix phase 1: per-block 391-bucket counts (LDS only) ----------------
__global__ __launch_bounds__(256) void k_countB(const int* __restrict__ dst, int* __restrict__ bh) {
    __shared__ unsigned h[NBINS];
    for (int r = threadIdx.x; r < NBINS; r += 256) h[r] = 0u;
    __syncthreads();
    int base = blockIdx.x * CHUNKB;
    int end = base + CHUNKB; if (end > N_EDGES) end = N_EDGES;
    for (int e = base + threadIdx.x; e < end; e += 256)
        atomicAdd(&h[dst[e] >> 8], 1u);
    __syncthreads();
    for (int r = threadIdx.x; r < NBINS; r += 256)
        bh[blockIdx.x * NBINS + r] = (int)h[r];
}

// ---------------- radix phase 2: hierarchical scan of 50K counts, bucket-major ----------------
__global__ __launch_bounds__(1024) void k_scanB1(const int* __restrict__ bh,
                                                 int* __restrict__ obh,
                                                 unsigned* __restrict__ bsumB) {
    __shared__ unsigned lds[1024];
    int t = threadIdx.x;
    int g = blockIdx.x * 1024 + t;
    unsigned v = 0u;
    int r = g >> 7, b = g & (NBLKB - 1);
    if (g < SCANTOT) v = (unsigned)bh[b * NBINS + r];
    lds[t] = v;
    __syncthreads();
    for (int d = 1; d < 1024; d <<= 1) {
        unsigned add = (t >= d) ? lds[t - d] : 0u;
        __syncthreads();
        lds[t] += add;
        __syncthreads();
    }
    if (g < SCANTOT) obh[b * NBINS + r] = (int)(lds[t] - v);   // local exclusive
    if (t == 1023) bsumB[blockIdx.x] = lds[t];
}

__global__ void k_scanB2(const unsigned* __restrict__ bsumB, unsigned* __restrict__ boffB) {
    __shared__ unsigned lds[64];
    int t = threadIdx.x;
    unsigned v = (t < SCANB_NB) ? bsumB[t] : 0u;
    lds[t] = v;
    __syncthreads();
    for (int d = 1; d < 64; d <<= 1) {
        unsigned add = (t >= d) ? lds[t - d] : 0u;
        __syncthreads();
        lds[t] += add;
        __syncthreads();
    }
    if (t < SCANB_NB) boffB[t] = lds[t] - v;
}

__global__ __launch_bounds__(1024) void k_scanB3(int* __restrict__ obh,
                                                 const unsigned* __restrict__ boffB,
                                                 int* __restrict__ bucketbase) {
    int t = threadIdx.x;
    int g = blockIdx.x * 1024 + t;
    if (g < SCANTOT) {
        int r = g >> 7, b = g & (NBLKB - 1);
        int val = obh[b * NBINS + r] + (int)boffB[blockIdx.x];
        obh[b * NBINS + r] = val;
        if (b == 0) bucketbase[r] = val;
    }
    if (g == 0) bucketbase[NBINS] = N_EDGES;
}

// ---------------- radix phase 3: scatter packed (dst,src) into private segments ----------------
__global__ __launch_bounds__(256) void k_binwriteB(const int* __restrict__ src, const int* __restrict__ dst,
                                                   const int* __restrict__ obh,
                                                   unsigned long long* __restrict__ bpack) {
    __shared__ unsigned pos[NBINS];
    for (int r = threadIdx.x; r < NBINS; r += 256)
        pos[r] = (unsigned)obh[blockIdx.x * NBINS + r];
    __syncthreads();
    int base = blockIdx.x * CHUNKB;
    int end = base + CHUNKB; if (end > N_EDGES) end = N_EDGES;
    for (int e = base + threadIdx.x; e < end; e += 256) {
        int d = dst[e];
        unsigned p = atomicAdd(&pos[d >> 8], 1u);
        bpack[p] = ((unsigned long long)(unsigned)d << 32) | (unsigned)src[e];
    }
}

// ---------------- radix phase 4: per-bucket in-LDS CSR (rowptr + esrc), no global atomics ----------------
__global__ __launch_bounds__(256) void k_bucket_csr(const unsigned long long* __restrict__ bpack,
                                                    const int* __restrict__ bucketbase,
                                                    int* __restrict__ rowptr,
                                                    int* __restrict__ esrc) {
    __shared__ unsigned c[256];
    int b = blockIdx.x;
    int t = threadIdx.x;
    int bb = bucketbase[b], be = bucketbase[b + 1];
    c[t] = 0u;
    __syncthreads();
    for (int i = bb + t; i < be; i += 256)
        atomicAdd(&c[(unsigned)(bpack[i] >> 32) & 255u], 1u);
    __syncthreads();
    unsigned own = c[t];
    for (int d = 1; d < 256; d <<= 1) {
        unsigned add = (t >= d) ? c[t - d] : 0u;
        __syncthreads();
        c[t] += add;
        __syncthreads();
    }
    unsigned excl = c[t] - own;
    int node = (b << 8) + t;
    if (node < N_NODES) rowptr[node] = bb + (int)excl;
    if (b == NBINS - 1 && t == 0) rowptr[N_NODES] = N_EDGES;
    __syncthreads();
    c[t] = excl;
    __syncthreads();
    for (int i = bb + t; i < be; i += 256) {
        unsigned long long p = bpack[i];
        unsigned slot = atomicAdd(&c[(unsigned)(p >> 32) & 255u], 1u);
        esrc[bb + (int)slot] = (int)(unsigned)p;
    }
}

// ---------------- merged weight pack (all 3 matrices in one launch) ----------------
// Bp[k8][col][8] k-major fragment layout for each.
__device__ __forceinline__ void pack_one(const float* Wl, const float* Wr, const float* bin,
                                         unsigned short* Bp, float* bout,
                                         int ncols_out, int ncols_src, int Keach, int idx) {
    int K = (Wr != nullptr) ? 2 * Keach : Keach;
    int col = idx / K, k = idx % K;
    float v = 0.f;
    if (col < ncols_src)
        v = (k < Keach) ? Wl[(size_t)k * ncols_src + col]
                        : Wr[(size_t)(k - Keach) * ncols_src + col];
    Bp[((size_t)(k >> 3) * ncols_out + col) * 8 + (k & 7)] = f2bf(v);
    if (k == 0) bout[col] = (col < ncols_src) ? bin[col] : 0.f;
}

#define PACK1 (FDIM * 256)
#define PACK2 (FDIM * 256)
#define PACK3 (NCLS_PAD * FDIM)
__global__ void k_pack_all(const float* __restrict__ W1l, const float* __restrict__ W1r,
                           const float* __restrict__ b1, unsigned short* __restrict__ Bp1, float* __restrict__ b1p,
                           const float* __restrict__ W2l, const float* __restrict__ W2r,
                           const float* __restrict__ b2, unsigned short* __restrict__ Bp2, float* __restrict__ b2p,
                           const float* __restrict__ Wout, const float* __restrict__ bo,
                           unsigned short* __restrict__ Bp3, float* __restrict__ b3p) {
    int idx = blockIdx.x * blockDim.x + threadIdx.x;
    if (idx < PACK1) { pack_one(W1l, W1r, b1, Bp1, b1p, FDIM, FDIM, FDIM, idx); return; }
    idx -= PACK1;
    if (idx < PACK2) { pack_one(W2l, W2r, b2, Bp2, b2p, FDIM, FDIM, FDIM, idx); return; }
    idx -= PACK2;
    if (idx < PACK3) { pack_one(Wout, nullptr, bo, Bp3, b3p, NCLS_PAD, NCLS, FDIM, idx); }
}

// ---------------- fused layer: aggregate 16 nodes/wave -> LDS -> GEMM -> relu -> bf16 out ----------
// Wave-private LDS tile; NO __syncthreads (wave w only touches Alds[w]).
// Bp: [k8=32][col=128][8]; K-halves: 0..127 = aggregated (Wl), 128..255 = root (Wr).
__global__ __launch_bounds__(256) void k_fused_layer(
        const unsigned short* __restrict__ feat,
        const int* __restrict__ esrc, const int* __restrict__ rowptr,
        const unsigned short* __restrict__ Bp, const float* __restrict__ bias,
        unsigned short* __restrict__ out) {
    __shared__ unsigned short Alds[4][16][LPAD];
    int wave = threadIdx.x >> 6, lane = threadIdx.x & 63;
    int sub = lane >> 4, fl = lane & 15;
    int wbase = blockIdx.x * 64 + wave * 16;

    // ---- phase 1: aggregate this wave's 16 nodes ----
    for (int n = 0; n < 16; ++n) {
        int node = wbase + n;
        float acc[8];
#pragma unroll
        for (int q = 0; q < 8; ++q) acc[q] = 0.f;
        int deg = 0;
        if (node < N_NODES) {
            int s = rowptr[node], e = rowptr[node + 1];
            deg = e - s;
            for (int j = s + sub; j < e; j += 4) {
                int sv = esrc[j];
                short8 v = *(const short8*)(feat + (size_t)sv * FDIM + fl * 8);
#pragma unroll
                for (int q = 0; q < 8; ++q) acc[q] += bf2f((unsigned short)v[q]);
            }
        }
#pragma unroll
        for (int q = 0; q < 8; ++q) {
            acc[q] += __shfl_xor(acc[q], 16, 64);
            acc[q] += __shfl_xor(acc[q], 32, 64);
        }
        if (sub == 0) {
            float inv = 1.0f / (float)(deg > 1 ? deg : 1);
            short8 o;
#pragma unroll
            for (int q = 0; q < 8; ++q) o[q] = (short)f2bf(acc[q] * inv);
            *(short8*)(&Alds[wave][n][fl * 8]) = o;
        }
    }

    // ---- phase 2: GEMM for this wave's 16 rows ----
    int lrow = lane & 15, kgrp = lane >> 4;
    int arow = wbase + lrow; if (arow > N_NODES - 1) arow = N_NODES - 1;
    f32x4 acc2[8];
#pragma unroll
    for (int c = 0; c < 8; ++c) acc2[c] = (f32x4){0.f, 0.f, 0.f, 0.f};

#pragma unroll
    for (int kb = 0; kb < 8; ++kb) {
        short8 a;
        if (kb < 4) a = *(const short8*)(&Alds[wave][lrow][kb * 32 + kgrp * 8]);
        else        a = *(const short8*)(feat + (size_t)arow * FDIM + (kb - 4) * 32 + kgrp * 8);
        int k8 = kb * 4 + kgrp;
        const unsigned short* brow = Bp + ((size_t)k8 * FDIM + lrow) * 8;
#pragma unroll
        for (int c = 0; c < 8; ++c) {
            short8 b = *(const short8*)(brow + c * 16 * 8);
            acc2[c] = __builtin_amdgcn_mfma_f32_16x16x32_bf16(a, b, acc2[c], 0, 0, 0);
        }
    }

    int orowbase = wbase + kgrp * 4;
#pragma unroll
    for (int c = 0; c < 8; ++c) {
        int col = c * 16 + lrow;
        float bv = bias[col];
#pragma unroll
        for (int i = 0; i < 4; ++i) {
            int r = orowbase + i;
            if (r < N_NODES) {
                float v = acc2[c][i] + bv;
                v = fmaxf(v, 0.f);
                out[(size_t)r * FDIM + col] = f2bf(v);
            }
        }
    }
}

// ---------------- fused final: aggregate -> layer-2 GEMM -> relu -> head GEMM -> fp32 out --------
__global__ __launch_bounds__(256) void k_fused_final(
        const unsigned short* __restrict__ feat,
        const int* __restrict__ esrc, const int* __restrict__ rowptr,
        const unsigned short* __restrict__ Bp, const float* __restrict__ bias,
        const unsigned short* __restrict__ Bp3, const float* __restrict__ bias3,
        float* __restrict__ out) {
    __shared__ unsigned short Alds[4][16][LPAD];
    int wave = threadIdx.x >> 6, lane = threadIdx.x & 63;
    int sub = lane >> 4, fl = lane & 15;
    int wbase = blockIdx.x * 64 + wave * 16;

    // ---- phase 1: aggregate ----
    for (int n = 0; n < 16; ++n) {
        int node = wbase + n;
        float acc[8];
#pragma unroll
        for (int q = 0; q < 8; ++q) acc[q] = 0.f;
        int deg = 0;
        if (node < N_NODES) {
            int s = rowptr[node], e = rowptr[node + 1];
            deg = e - s;
            for (int j = s + sub; j < e; j += 4) {
                int sv = esrc[j];
                short8 v = *(const short8*)(feat + (size_t)sv * FDIM + fl * 8);
#pragma unroll
                for (int q = 0; q < 8; ++q) acc[q] += bf2f((unsigned short)v[q]);
            }
        }
#pragma unroll
        for (int q = 0; q < 8; ++q) {
            acc[q] += __shfl_xor(acc[q], 16, 64);
            acc[q] += __shfl_xor(acc[q], 32, 64);
        }
        if (sub == 0) {
            float inv = 1.0f / (float)(deg > 1 ? deg : 1);
            short8 o;
#pragma unroll
            for (int q = 0; q < 8; ++q) o[q] = (short)f2bf(acc[q] * inv);
            *(short8*)(&Alds[wave][n][fl * 8]) = o;
        }
    }

    // ---- phase 2: layer-2 GEMM ----
    int lrow = lane & 15, kgrp = lane >> 4;
    int arow = wbase + lrow; if (arow > N_NODES - 1) arow = N_NODES - 1;
    f32x4 acc2[8];
#pragma unroll
    for (int c = 0; c < 8; ++c) acc2[c] = (f32x4){0.f, 0.f, 0.f, 0.f};

#pragma unroll
    for (int kb = 0; kb < 8; ++kb) {
        short8 a;
        if (kb < 4) a = *(const short8*)(&Alds[wave][lrow][kb * 32 + kgrp * 8]);
        else        a = *(const short8*)(feat + (size_t)arow * FDIM + (kb - 4) * 32 + kgrp * 8);
        int k8 = kb * 4 + kgrp;
        const unsigned short* brow = Bp + ((size_t)k8 * FDIM + lrow) * 8;
#pragma unroll
        for (int c = 0; c < 8; ++c) {
            short8 b = *(const short8*)(brow + c * 16 * 8);
            acc2[c] = __builtin_amdgcn_mfma_f32_16x16x32_bf16(a, b, acc2[c], 0, 0, 0);
        }
    }

    // ---- stage h2 tile back into this wave's LDS region (bf16, relu+bias applied) ----
    int srowbase = kgrp * 4;   // row within tile
#pragma unroll
    for (int c = 0; c < 8; ++c) {
        int col = c * 16 + lrow;
        float bv = bias[col];
#pragma unroll
        for (int i = 0; i < 4; ++i) {
            float v = acc2[c][i] + bv;
            v = fmaxf(v, 0.f);
            Alds[wave][srowbase + i][col] = f2bf(v);
        }
    }

    // ---- phase 3: head GEMM (K=128, 48 cols) ----
    f32x4 acc3[3];
#pragma unroll
    for (int c = 0; c < 3; ++c) acc3[c] = (f32x4){0.f, 0.f, 0.f, 0.f};

#pragma unroll
    for (int kb = 0; kb < 4; ++kb) {
        short8 a = *(const short8*)(&Alds[wave][lrow][kb * 32 + kgrp * 8]);
        int k8 = kb * 4 + kgrp;
        const unsigned short* brow = Bp3 + ((size_t)k8 * NCLS_PAD + lrow) * 8;
#pragma unroll
        for (int c = 0; c < 3; ++c) {
            short8 b = *(const short8*)(brow + c * 16 * 8);
            acc3[c] = __builtin_amdgcn_mfma_f32_16x16x32_bf16(a, b, acc3[c], 0, 0, 0);
        }
    }

    int orowbase = wbase + kgrp * 4;
#pragma unroll
    for (int c = 0; c < 3; ++c) {
        int col = c * 16 + lrow;
        if (col < NCLS) {
            float bv = bias3[col];
#pragma unroll
            for (int i = 0; i < 4; ++i) {
                int r = orowbase + i;
                if (r < N_NODES)
                    out[(size_t)r * NCLS + col] = acc3[c][i] + bv;
            }
        }
    }
}

extern "C" void kernel_launch(void* const* d_in, const int* in_sizes, int n_in,
                              void* d_out, int out_size, void* d_ws, size_t ws_size,
                              hipStream_t stream) {
    const float* x    = (const float*)d_in[0];
    const int*   ei   = (const int*)d_in[1];
    const float* W1l  = (const float*)d_in[2];
    const float* W1r  = (const float*)d_in[3];
    const float* b1   = (const float*)d_in[4];
    const float* W2l  = (const float*)d_in[5];
    const float* W2r  = (const float*)d_in[6];
    const float* b2   = (const float*)d_in[7];
    const float* Wout = (const float*)d_in[8];
    const float* bout = (const float*)d_in[9];
    const int* src = ei;
    const int* dst = ei + N_EDGES;

    char* ws = (char*)d_ws;
    size_t off = 0;
    auto alloc = [&](size_t bytes) -> void* {
        void* p = ws + off;
        off += (bytes + 255) & ~(size_t)255;
        return p;
    };
    unsigned short* xb   = (unsigned short*)alloc((size_t)N_NODES * FDIM * 2);
    unsigned short* h1   = (unsigned short*)alloc((size_t)N_NODES * FDIM * 2);
    unsigned short* Bp1  = (unsigned short*)alloc((size_t)FDIM * 256 * 2);
    unsigned short* Bp2  = (unsigned short*)alloc((size_t)FDIM * 256 * 2);
    unsigned short* Bp3  = (unsigned short*)alloc((size_t)NCLS_PAD * FDIM * 2);
    float* b1p = (float*)alloc(FDIM * 4);
    float* b2p = (float*)alloc(FDIM * 4);
    float* b3p = (float*)alloc(NCLS_PAD * 4);
    int* rowptr    = (int*)alloc((size_t)(N_NODES + 1) * 4);
    int* esrc      = (int*)alloc((size_t)N_EDGES * 4);
    int* bh        = (int*)alloc((size_t)NBLKB * NBINS * 4);
    int* obh       = (int*)alloc((size_t)NBLKB * NBINS * 4);
    int* bucketbase= (int*)alloc((size_t)(NBINS + 1) * 4);
    unsigned* bsumB = (unsigned*)alloc((size_t)SCANB_NB * 4);
    unsigned* boffB = (unsigned*)alloc((size_t)SCANB_NB * 4);
    unsigned long long* bpack = (unsigned long long*)alloc((size_t)N_EDGES * 8);

    // bf16 copy of x
    int n4 = N_NODES * FDIM / 4;
    k_cvt_bf16<<<(n4 + 255) / 256, 256, 0, stream>>>((const float4*)x, (ushort4*)xb, n4);

    // merged weight packs
    int packTot = PACK1 + PACK2 + PACK3;
    k_pack_all<<<(packTot + 255) / 256, 256, 0, stream>>>(
        W1l, W1r, b1, Bp1, b1p, W2l, W2r, b2, Bp2, b2p, Wout, bout, Bp3, b3p);

    // CSR build: 391-bucket radix partition + per-bucket in-LDS finish
    k_countB<<<NBLKB, 256, 0, stream>>>(dst, bh);
    k_scanB1<<<SCANB_NB, 1024, 0, stream>>>(bh, obh, bsumB);
    k_scanB2<<<1, 64, 0, stream>>>(bsumB, boffB);
    k_scanB3<<<SCANB_NB, 1024, 0, stream>>>(obh, boffB, bucketbase);
    k_binwriteB<<<NBLKB, 256, 0, stream>>>(src, dst, obh, bpack);
    k_bucket_csr<<<NBINS, 256, 0, stream>>>(bpack, bucketbase, rowptr, esrc);

    int fusedGrid = (N_NODES + 63) / 64;

    // layer 1 (agg + GEMM fused)
    k_fused_layer<<<fusedGrid, 256, 0, stream>>>(xb, esrc, rowptr, Bp1, b1p, h1);
    // layer 2 + head (agg + GEMM + head fused)
    k_fused_final<<<fusedGrid, 256, 0, stream>>>(h1, esrc, rowptr, Bp2, b2p, Bp3, b3p, (float*)d_out);
}

// Round 10
// 266.009 us; speedup vs baseline: 1.3281x; 1.3281x over previous
//
#include <hip/hip_runtime.h>
#include <hip/hip_bf16.h>

#define N_NODES 100000
#define N_EDGES 1600000
#define FDIM 128
#define NCLS 40
#define NCLS_PAD 48

#define NBINS ((N_NODES + 255) / 256)        // 391 buckets of 256 nodes
#define NBLKB 128                            // partition blocks
#define CHUNKB (N_EDGES / NBLKB)             // 12500 edges per block
#define SCANTOT (NBINS * NBLKB)              // 50048
#define SCANB_NB ((SCANTOT + 1023) / 1024)   // 49

#define LPAD 136                             // LDS row pad (272B row stride -> 2-way max, free)

#define PACK1 (FDIM * 256)
#define PACK2 (FDIM * 256)
#define PACK3 (NCLS_PAD * FDIM)
#define PACKTOT (PACK1 + PACK2 + PACK3)      // 71680
#define PACK_NB ((PACKTOT + 255) / 256)      // 280
#define CVT_N4 (N_NODES * FDIM / 4)          // 3.2M
#define CVT_NB ((CVT_N4 + 255) / 256)        // 12500

typedef __attribute__((ext_vector_type(8))) short short8;
typedef __attribute__((ext_vector_type(4))) float f32x4;

__device__ __forceinline__ float bf2f(unsigned short u) {
    union { unsigned int i; float f; } v; v.i = ((unsigned int)u) << 16; return v.f;
}
__device__ __forceinline__ unsigned short f2bf(float f) {
    __hip_bfloat16 h = __float2bfloat16(f);
    return *reinterpret_cast<unsigned short*>(&h);
}

// ---------------- merged weight pack helper ----------------
__device__ __forceinline__ void pack_one(const float* Wl, const float* Wr, const float* bin,
                                         unsigned short* Bp, float* bout,
                                         int ncols_out, int ncols_src, int Keach, int idx) {
    int K = (Wr != nullptr) ? 2 * Keach : Keach;
    int col = idx / K, k = idx % K;
    float v = 0.f;
    if (col < ncols_src)
        v = (k < Keach) ? Wl[(size_t)k * ncols_src + col]
                        : Wr[(size_t)(k - Keach) * ncols_src + col];
    Bp[((size_t)(k >> 3) * ncols_out + col) * 8 + (k & 7)] = f2bf(v);
    if (k == 0) bout[col] = (col < ncols_src) ? bin[col] : 0.f;
}

// ---------------- prologue: countB | cvt | pack, role by blockIdx ----------------
__global__ __launch_bounds__(256) void k_prologue(
        const int* __restrict__ dst, int* __restrict__ bh,
        const float4* __restrict__ x4, ushort4* __restrict__ xb4,
        const float* __restrict__ W1l, const float* __restrict__ W1r,
        const float* __restrict__ b1, unsigned short* __restrict__ Bp1, float* __restrict__ b1p,
        const float* __restrict__ W2l, const float* __restrict__ W2r,
        const float* __restrict__ b2, unsigned short* __restrict__ Bp2, float* __restrict__ b2p,
        const float* __restrict__ Wout, const float* __restrict__ bo,
        unsigned short* __restrict__ Bp3, float* __restrict__ b3p) {
    __shared__ unsigned h[NBINS];
    int b = blockIdx.x;
    if (b < NBLKB) {
        // --- 391-bucket per-block histogram ---
        for (int r = threadIdx.x; r < NBINS; r += 256) h[r] = 0u;
        __syncthreads();
        int base = b * CHUNKB;
        int end = base + CHUNKB; if (end > N_EDGES) end = N_EDGES;
        for (int e = base + threadIdx.x; e < end; e += 256)
            atomicAdd(&h[dst[e] >> 8], 1u);
        __syncthreads();
        for (int r = threadIdx.x; r < NBINS; r += 256)
            bh[b * NBINS + r] = (int)h[r];
        return;
    }
    b -= NBLKB;
    if (b < CVT_NB) {
        int i = b * 256 + threadIdx.x;
        if (i < CVT_N4) {
            float4 v = x4[i];
            ushort4 o;
            o.x = f2bf(v.x); o.y = f2bf(v.y); o.z = f2bf(v.z); o.w = f2bf(v.w);
            xb4[i] = o;
        }
        return;
    }
    b -= CVT_NB;
    int idx = b * 256 + threadIdx.x;
    if (idx < PACK1) { pack_one(W1l, W1r, b1, Bp1, b1p, FDIM, FDIM, FDIM, idx); return; }
    idx -= PACK1;
    if (idx < PACK2) { pack_one(W2l, W2r, b2, Bp2, b2p, FDIM, FDIM, FDIM, idx); return; }
    idx -= PACK2;
    if (idx < PACK3) { pack_one(Wout, nullptr, bo, Bp3, b3p, NCLS_PAD, NCLS, FDIM, idx); }
}

// ---------------- radix scan phase 1: local scan of 50K counts, bucket-major ----------------
__global__ __launch_bounds__(1024) void k_scanB1(const int* __restrict__ bh,
                                                 int* __restrict__ obh,
                                                 unsigned* __restrict__ bsumB) {
    __shared__ unsigned lds[1024];
    int t = threadIdx.x;
    int g = blockIdx.x * 1024 + t;
    unsigned v = 0u;
    int r = g >> 7, b = g & (NBLKB - 1);
    if (g < SCANTOT) v = (unsigned)bh[b * NBINS + r];
    lds[t] = v;
    __syncthreads();
    for (int d = 1; d < 1024; d <<= 1) {
        unsigned add = (t >= d) ? lds[t - d] : 0u;
        __syncthreads();
        lds[t] += add;
        __syncthreads();
    }
    if (g < SCANTOT) obh[b * NBINS + r] = (int)(lds[t] - v);   // local exclusive
    if (t == 1023) bsumB[blockIdx.x] = lds[t];
}

// ---------------- radix scan phase 2 (merged): each block re-derives block offsets ----------------
__global__ __launch_bounds__(1024) void k_scanB3(int* __restrict__ obh,
                                                 const unsigned* __restrict__ bsumB,
                                                 int* __restrict__ bucketbase) {
    __shared__ unsigned soff[SCANB_NB];
    int t = threadIdx.x;
    if (t < SCANB_NB) soff[t] = bsumB[t];
    __syncthreads();
    if (t == 0) {
        unsigned run = 0;
        for (int i = 0; i < SCANB_NB; ++i) { unsigned v = soff[i]; soff[i] = run; run += v; }
    }
    __syncthreads();
    int g = blockIdx.x * 1024 + t;
    if (g < SCANTOT) {
        int r = g >> 7, b = g & (NBLKB - 1);
        int val = obh[b * NBINS + r] + (int)soff[blockIdx.x];
        obh[b * NBINS + r] = val;
        if (b == 0) bucketbase[r] = val;
    }
    if (g == 0) bucketbase[NBINS] = N_EDGES;
}

// ---------------- radix phase 3: scatter packed (dst,src) into private segments ----------------
__global__ __launch_bounds__(256) void k_binwriteB(const int* __restrict__ src, const int* __restrict__ dst,
                                                   const int* __restrict__ obh,
                                                   unsigned long long* __restrict__ bpack) {
    __shared__ unsigned pos[NBINS];
    for (int r = threadIdx.x; r < NBINS; r += 256)
        pos[r] = (unsigned)obh[blockIdx.x * NBINS + r];
    __syncthreads();
    int base = blockIdx.x * CHUNKB;
    int end = base + CHUNKB; if (end > N_EDGES) end = N_EDGES;
    for (int e = base + threadIdx.x; e < end; e += 256) {
        int d = dst[e];
        unsigned p = atomicAdd(&pos[d >> 8], 1u);
        bpack[p] = ((unsigned long long)(unsigned)d << 32) | (unsigned)src[e];
    }
}

// ---------------- radix phase 4: per-bucket in-LDS CSR (rowptr + esrc) ----------------
__global__ __launch_bounds__(256) void k_bucket_csr(const unsigned long long* __restrict__ bpack,
                                                    const int* __restrict__ bucketbase,
                                                    int* __restrict__ rowptr,
                                                    int* __restrict__ esrc) {
    __shared__ unsigned c[256];
    int b = blockIdx.x;
    int t = threadIdx.x;
    int bb = bucketbase[b], be = bucketbase[b + 1];
    c[t] = 0u;
    __syncthreads();
    for (int i = bb + t; i < be; i += 256)
        atomicAdd(&c[(unsigned)(bpack[i] >> 32) & 255u], 1u);
    __syncthreads();
    unsigned own = c[t];
    for (int d = 1; d < 256; d <<= 1) {
        unsigned add = (t >= d) ? c[t - d] : 0u;
        __syncthreads();
        c[t] += add;
        __syncthreads();
    }
    unsigned excl = c[t] - own;
    int node = (b << 8) + t;
    if (node < N_NODES) rowptr[node] = bb + (int)excl;
    if (b == NBINS - 1 && t == 0) rowptr[N_NODES] = N_EDGES;
    __syncthreads();
    c[t] = excl;
    __syncthreads();
    for (int i = bb + t; i < be; i += 256) {
        unsigned long long p = bpack[i];
        unsigned slot = atomicAdd(&c[(unsigned)(p >> 32) & 255u], 1u);
        esrc[bb + (int)slot] = (int)(unsigned)p;
    }
}

// ---------------- mean aggregation (one wave per node -> max parallelism) ----------------
__global__ void k_aggregate(const unsigned short* __restrict__ feat,
                            const int* __restrict__ esrc,
                            const int* __restrict__ rowptr,
                            unsigned short* __restrict__ out) {
    int node = blockIdx.x * 4 + (threadIdx.x >> 6);
    if (node >= N_NODES) return;
    int lane = threadIdx.x & 63;
    int sub = lane >> 4;
    int fl = lane & 15;
    int s = rowptr[node], e = rowptr[node + 1];
    float acc[8];
#pragma unroll
    for (int q = 0; q < 8; ++q) acc[q] = 0.f;

    for (int j = s + sub; j < e; j += 4) {
        int sv = esrc[j];
        short8 v = *(const short8*)(feat + (size_t)sv * FDIM + fl * 8);
#pragma unroll
        for (int q = 0; q < 8; ++q) acc[q] += bf2f((unsigned short)v[q]);
    }
#pragma unroll
    for (int q = 0; q < 8; ++q) {
        acc[q] += __shfl_xor(acc[q], 16, 64);
        acc[q] += __shfl_xor(acc[q], 32, 64);
    }
    int deg = e - s;
    float inv = 1.0f / (float)(deg > 1 ? deg : 1);
    if (sub == 0) {
        short8 o;
#pragma unroll
        for (int q = 0; q < 8; ++q) o[q] = (short)f2bf(acc[q] * inv);
        *(short8*)(out + (size_t)node * FDIM + fl * 8) = o;
    }
}

// ---------------- layer-1 GEMM: out = relu([A0 | A1] @ W + bias), bf16 out ----------------
// Bp layout: [k8=32][col=128][8] bf16 (k-major fragments, coalesced B loads).
__global__ __launch_bounds__(256) void k_gemm_layer(
        const unsigned short* __restrict__ A0, const unsigned short* __restrict__ A1,
        const unsigned short* __restrict__ Bp, const float* __restrict__ bias,
        unsigned short* __restrict__ out) {
    int wave = threadIdx.x >> 6;
    int lane = threadIdx.x & 63;
    int rowblk = blockIdx.x * 64 + wave * 16;
    int lrow = lane & 15;
    int kgrp = lane >> 4;
    int arow = rowblk + lrow; if (arow > N_NODES - 1) arow = N_NODES - 1;

    f32x4 acc[8];
#pragma unroll
    for (int c = 0; c < 8; ++c) acc[c] = (f32x4){0.f, 0.f, 0.f, 0.f};

#pragma unroll
    for (int kb = 0; kb < 8; ++kb) {
        const unsigned short* Asrc = (kb < 4) ? A0 : A1;
        int kk = (kb & 3) * 32 + kgrp * 8;
        short8 a = *(const short8*)(Asrc + (size_t)arow * FDIM + kk);
        int k8 = kb * 4 + kgrp;
        const unsigned short* brow = Bp + ((size_t)k8 * FDIM + lrow) * 8;
#pragma unroll
        for (int c = 0; c < 8; ++c) {
            short8 b = *(const short8*)(brow + c * 16 * 8);
            acc[c] = __builtin_amdgcn_mfma_f32_16x16x32_bf16(a, b, acc[c], 0, 0, 0);
        }
    }

    int orowbase = rowblk + kgrp * 4;
#pragma unroll
    for (int c = 0; c < 8; ++c) {
        int col = c * 16 + lrow;
        float bv = bias[col];
#pragma unroll
        for (int i = 0; i < 4; ++i) {
            int r = orowbase + i;
            if (r < N_NODES) {
                float v = acc[c][i] + bv;
                v = fmaxf(v, 0.f);
                out[(size_t)r * FDIM + col] = f2bf(v);
            }
        }
    }
}

// ---------------- final: layer-2 GEMM + relu -> LDS -> head GEMM -> fp32 out ----------------
// No aggregation inside (A0/A1 from global); wave-private LDS staging, no __syncthreads.
__global__ __launch_bounds__(256) void k_gemm_final(
        const unsigned short* __restrict__ A0, const unsigned short* __restrict__ A1,
        const unsigned short* __restrict__ Bp, const float* __restrict__ bias,
        const unsigned short* __restrict__ Bp3, const float* __restrict__ bias3,
        float* __restrict__ out) {
    __shared__ unsigned short Alds[4][16][LPAD];
    int wave = threadIdx.x >> 6;
    int lane = threadIdx.x & 63;
    int rowblk = blockIdx.x * 64 + wave * 16;
    int lrow = lane & 15;
    int kgrp = lane >> 4;
    int arow = rowblk + lrow; if (arow > N_NODES - 1) arow = N_NODES - 1;

    f32x4 acc2[8];
#pragma unroll
    for (int c = 0; c < 8; ++c) acc2[c] = (f32x4){0.f, 0.f, 0.f, 0.f};

#pragma unroll
    for (int kb = 0; kb < 8; ++kb) {
        const unsigned short* Asrc = (kb < 4) ? A0 : A1;
        int kk = (kb & 3) * 32 + kgrp * 8;
        short8 a = *(const short8*)(Asrc + (size_t)arow * FDIM + kk);
        int k8 = kb * 4 + kgrp;
        const unsigned short* brow = Bp + ((size_t)k8 * FDIM + lrow) * 8;
#pragma unroll
        for (int c = 0; c < 8; ++c) {
            short8 b = *(const short8*)(brow + c * 16 * 8);
            acc2[c] = __builtin_amdgcn_mfma_f32_16x16x32_bf16(a, b, acc2[c], 0, 0, 0);
        }
    }

    // stage relu(h2) tile into this wave's LDS region (bf16)
    int srowbase = kgrp * 4;
#pragma unroll
    for (int c = 0; c < 8; ++c) {
        int col = c * 16 + lrow;
        float bv = bias[col];
#pragma unroll
        for (int i = 0; i < 4; ++i) {
            float v = acc2[c][i] + bv;
            v = fmaxf(v, 0.f);
            Alds[wave][srowbase + i][col] = f2bf(v);
        }
    }

    // head GEMM (K=128, 48 padded cols)
    f32x4 acc3[3];
#pragma unroll
    for (int c = 0; c < 3; ++c) acc3[c] = (f32x4){0.f, 0.f, 0.f, 0.f};

#pragma unroll
    for (int kb = 0; kb < 4; ++kb) {
        short8 a = *(const short8*)(&Alds[wave][lrow][kb * 32 + kgrp * 8]);
        int k8 = kb * 4 + kgrp;
        const unsigned short* brow = Bp3 + ((size_t)k8 * NCLS_PAD + lrow) * 8;
#pragma unroll
        for (int c = 0; c < 3; ++c) {
            short8 b = *(const short8*)(brow + c * 16 * 8);
            acc3[c] = __builtin_amdgcn_mfma_f32_16x16x32_bf16(a, b, acc3[c], 0, 0, 0);
        }
    }

    int orowbase = rowblk + kgrp * 4;
#pragma unroll
    for (int c = 0; c < 3; ++c) {
        int col = c * 16 + lrow;
        if (col < NCLS) {
            float bv = bias3[col];
#pragma unroll
            for (int i = 0; i < 4; ++i) {
                int r = orowbase + i;
                if (r < N_NODES)
                    out[(size_t)r * NCLS + col] = acc3[c][i] + bv;
            }
        }
    }
}

extern "C" void kernel_launch(void* const* d_in, const int* in_sizes, int n_in,
                              void* d_out, int out_size, void* d_ws, size_t ws_size,
                              hipStream_t stream) {
    const float* x    = (const float*)d_in[0];
    const int*   ei   = (const int*)d_in[1];
    const float* W1l  = (const float*)d_in[2];
    const float* W1r  = (const float*)d_in[3];
    const float* b1   = (const float*)d_in[4];
    const float* W2l  = (const float*)d_in[5];
    const float* W2r  = (const float*)d_in[6];
    const float* b2   = (const float*)d_in[7];
    const float* Wout = (const float*)d_in[8];
    const float* bout = (const float*)d_in[9];
    const int* src = ei;
    const int* dst = ei + N_EDGES;

    char* ws = (char*)d_ws;
    size_t off = 0;
    auto alloc = [&](size_t bytes) -> void* {
        void* p = ws + off;
        off += (bytes + 255) & ~(size_t)255;
        return p;
    };
    unsigned short* xb   = (unsigned short*)alloc((size_t)N_NODES * FDIM * 2);
    unsigned short* aggn = (unsigned short*)alloc((size_t)N_NODES * FDIM * 2);
    unsigned short* h1   = (unsigned short*)alloc((size_t)N_NODES * FDIM * 2);
    unsigned short* Bp1  = (unsigned short*)alloc((size_t)FDIM * 256 * 2);
    unsigned short* Bp2  = (unsigned short*)alloc((size_t)FDIM * 256 * 2);
    unsigned short* Bp3  = (unsigned short*)alloc((size_t)NCLS_PAD * FDIM * 2);
    float* b1p = (float*)alloc(FDIM * 4);
    float* b2p = (float*)alloc(FDIM * 4);
    float* b3p = (float*)alloc(NCLS_PAD * 4);
    int* rowptr    = (int*)alloc((size_t)(N_NODES + 1) * 4);
    int* esrc      = (int*)alloc((size_t)N_EDGES * 4);
    int* bh        = (int*)alloc((size_t)NBLKB * NBINS * 4);
    int* obh       = (int*)alloc((size_t)NBLKB * NBINS * 4);
    int* bucketbase= (int*)alloc((size_t)(NBINS + 1) * 4);
    unsigned* bsumB = (unsigned*)alloc((size_t)SCANB_NB * 4);
    unsigned long long* bpack = (unsigned long long*)alloc((size_t)N_EDGES * 8);

    // prologue: histogram | bf16 convert | weight packs (all independent)
    int proGrid = NBLKB + CVT_NB + PACK_NB;
    k_prologue<<<proGrid, 256, 0, stream>>>(
        dst, bh, (const float4*)x, (ushort4*)xb,
        W1l, W1r, b1, Bp1, b1p, W2l, W2r, b2, Bp2, b2p, Wout, bout, Bp3, b3p);

    // CSR build
    k_scanB1<<<SCANB_NB, 1024, 0, stream>>>(bh, obh, bsumB);
    k_scanB3<<<SCANB_NB, 1024, 0, stream>>>(obh, bsumB, bucketbase);
    k_binwriteB<<<NBLKB, 256, 0, stream>>>(src, dst, obh, bpack);
    k_bucket_csr<<<NBINS, 256, 0, stream>>>(bpack, bucketbase, rowptr, esrc);

    int aggGrid = (N_NODES + 3) / 4;
    int gemmGrid = (N_NODES + 63) / 64;

    // layer 1
    k_aggregate<<<aggGrid, 256, 0, stream>>>(xb, esrc, rowptr, aggn);
    k_gemm_layer<<<gemmGrid, 256, 0, stream>>>(aggn, xb, Bp1, b1p, h1);
    // layer 2 + head
    k_aggregate<<<aggGrid, 256, 0, stream>>>(h1, esrc, rowptr, aggn);
    k_gemm_final<<<gemmGrid, 256, 0, stream>>>(aggn, h1, Bp2, b2p, Bp3, b3p, (float*)d_out);
}

// Round 11
// 250.893 us; speedup vs baseline: 1.4081x; 1.0602x over previous
//
#include <hip/hip_runtime.h>
#include <hip/hip_bf16.h>

#define N_NODES 100000
#define N_EDGES 1600000
#define FDIM 128
#define NCLS 40
#define NCLS_PAD 48

#define NBINS ((N_NODES + 255) / 256)        // 391 buckets of 256 nodes
#define NBLKB 128                            // partition blocks
#define CHUNKB (N_EDGES / NBLKB)             // 12500 edges per block
#define SCANTOT (NBINS * NBLKB)              // 50048
#define SCANB_NB ((SCANTOT + 1023) / 1024)   // 49

#define LPAD 136                             // LDS row pad (272B row stride -> 2-way max, free)

#define PACK1 (FDIM * 256)
#define PACK2 (FDIM * 256)
#define PACK3 (NCLS_PAD * FDIM)
#define PACKTOT (PACK1 + PACK2 + PACK3)      // 71680
#define PACK_NB ((PACKTOT + 255) / 256)      // 280
#define CVT_N4 (N_NODES * FDIM / 4)          // 3.2M
#define CVT_NB ((CVT_N4 + 255) / 256)        // 12500

typedef __attribute__((ext_vector_type(8))) short short8;
typedef __attribute__((ext_vector_type(4))) float f32x4;

__device__ __forceinline__ float bf2f(unsigned short u) {
    union { unsigned int i; float f; } v; v.i = ((unsigned int)u) << 16; return v.f;
}
__device__ __forceinline__ unsigned short f2bf(float f) {
    __hip_bfloat16 h = __float2bfloat16(f);
    return *reinterpret_cast<unsigned short*>(&h);
}

// ---------------- merged weight pack helper ----------------
__device__ __forceinline__ void pack_one(const float* Wl, const float* Wr, const float* bin,
                                         unsigned short* Bp, float* bout,
                                         int ncols_out, int ncols_src, int Keach, int idx) {
    int K = (Wr != nullptr) ? 2 * Keach : Keach;
    int col = idx / K, k = idx % K;
    float v = 0.f;
    if (col < ncols_src)
        v = (k < Keach) ? Wl[(size_t)k * ncols_src + col]
                        : Wr[(size_t)(k - Keach) * ncols_src + col];
    Bp[((size_t)(k >> 3) * ncols_out + col) * 8 + (k & 7)] = f2bf(v);
    if (k == 0) bout[col] = (col < ncols_src) ? bin[col] : 0.f;
}

// ---------------- prologue: countB | cvt | pack, role by blockIdx ----------------
__global__ __launch_bounds__(256) void k_prologue(
        const int* __restrict__ dst, int* __restrict__ bh,
        const float4* __restrict__ x4, ushort4* __restrict__ xb4,
        const float* __restrict__ W1l, const float* __restrict__ W1r,
        const float* __restrict__ b1, unsigned short* __restrict__ Bp1, float* __restrict__ b1p,
        const float* __restrict__ W2l, const float* __restrict__ W2r,
        const float* __restrict__ b2, unsigned short* __restrict__ Bp2, float* __restrict__ b2p,
        const float* __restrict__ Wout, const float* __restrict__ bo,
        unsigned short* __restrict__ Bp3, float* __restrict__ b3p) {
    __shared__ unsigned h[NBINS];
    int b = blockIdx.x;
    if (b < NBLKB) {
        for (int r = threadIdx.x; r < NBINS; r += 256) h[r] = 0u;
        __syncthreads();
        int base = b * CHUNKB;
        int end = base + CHUNKB; if (end > N_EDGES) end = N_EDGES;
        for (int e = base + threadIdx.x; e < end; e += 256)
            atomicAdd(&h[dst[e] >> 8], 1u);
        __syncthreads();
        for (int r = threadIdx.x; r < NBINS; r += 256)
            bh[b * NBINS + r] = (int)h[r];
        return;
    }
    b -= NBLKB;
    if (b < CVT_NB) {
        int i = b * 256 + threadIdx.x;
        if (i < CVT_N4) {
            float4 v = x4[i];
            ushort4 o;
            o.x = f2bf(v.x); o.y = f2bf(v.y); o.z = f2bf(v.z); o.w = f2bf(v.w);
            xb4[i] = o;
        }
        return;
    }
    b -= CVT_NB;
    int idx = b * 256 + threadIdx.x;
    if (idx < PACK1) { pack_one(W1l, W1r, b1, Bp1, b1p, FDIM, FDIM, FDIM, idx); return; }
    idx -= PACK1;
    if (idx < PACK2) { pack_one(W2l, W2r, b2, Bp2, b2p, FDIM, FDIM, FDIM, idx); return; }
    idx -= PACK2;
    if (idx < PACK3) { pack_one(Wout, nullptr, bo, Bp3, b3p, NCLS_PAD, NCLS, FDIM, idx); }
}

// ---------------- radix scan phase 1: shfl-based local scan (1 barrier pair vs 20) ----------------
__global__ __launch_bounds__(1024) void k_scanB1(const int* __restrict__ bh,
                                                 int* __restrict__ obh,
                                                 unsigned* __restrict__ bsumB) {
    __shared__ unsigned wsums[16];
    int t = threadIdx.x;
    int wave = t >> 6, lane = t & 63;
    int g = blockIdx.x * 1024 + t;
    unsigned v = 0u;
    int r = g >> 7, b = g & (NBLKB - 1);
    if (g < SCANTOT) v = (unsigned)bh[b * NBINS + r];
    unsigned val = v;
#pragma unroll
    for (int d = 1; d < 64; d <<= 1) {
        unsigned n = __shfl_up(val, d, 64);
        if (lane >= d) val += n;
    }
    if (lane == 63) wsums[wave] = val;
    __syncthreads();
    if (t < 16) {
        unsigned wv = wsums[t];
#pragma unroll
        for (int d = 1; d < 16; d <<= 1) {
            unsigned n = __shfl_up(wv, d, 64);
            if (t >= d) wv += n;
        }
        wsums[t] = wv;
    }
    __syncthreads();
    unsigned waveoff = (wave > 0) ? wsums[wave - 1] : 0u;
    if (g < SCANTOT) obh[b * NBINS + r] = (int)(waveoff + val - v);
    if (t == 1023) bsumB[blockIdx.x] = wsums[15];
}

// ---------------- radix scan phase 2 (merged): each block re-derives block offsets ----------------
__global__ __launch_bounds__(1024) void k_scanB3(int* __restrict__ obh,
                                                 const unsigned* __restrict__ bsumB,
                                                 int* __restrict__ bucketbase) {
    __shared__ unsigned soff[SCANB_NB];
    int t = threadIdx.x;
    if (t < SCANB_NB) soff[t] = bsumB[t];
    __syncthreads();
    if (t == 0) {
        unsigned run = 0;
        for (int i = 0; i < SCANB_NB; ++i) { unsigned v = soff[i]; soff[i] = run; run += v; }
    }
    __syncthreads();
    int g = blockIdx.x * 1024 + t;
    if (g < SCANTOT) {
        int r = g >> 7, b = g & (NBLKB - 1);
        int val = obh[b * NBINS + r] + (int)soff[blockIdx.x];
        obh[b * NBINS + r] = val;
        if (b == 0) bucketbase[r] = val;
    }
    if (g == 0) bucketbase[NBINS] = N_EDGES;
}

// ---------------- radix phase 3: scatter packed (dst,src) into private segments ----------------
__global__ __launch_bounds__(256) void k_binwriteB(const int* __restrict__ src, const int* __restrict__ dst,
                                                   const int* __restrict__ obh,
                                                   unsigned long long* __restrict__ bpack) {
    __shared__ unsigned pos[NBINS];
    for (int r = threadIdx.x; r < NBINS; r += 256)
        pos[r] = (unsigned)obh[blockIdx.x * NBINS + r];
    __syncthreads();
    int base = blockIdx.x * CHUNKB;
    int end = base + CHUNKB; if (end > N_EDGES) end = N_EDGES;
    for (int e = base + threadIdx.x; e < end; e += 256) {
        int d = dst[e];
        unsigned p = atomicAdd(&pos[d >> 8], 1u);
        bpack[p] = ((unsigned long long)(unsigned)d << 32) | (unsigned)src[e];
    }
}

// ---------------- radix phase 4: per-bucket in-LDS CSR (shfl scan) ----------------
__global__ __launch_bounds__(256) void k_bucket_csr(const unsigned long long* __restrict__ bpack,
                                                    const int* __restrict__ bucketbase,
                                                    int* __restrict__ rowptr,
                                                    int* __restrict__ esrc) {
    __shared__ unsigned c[256];
    __shared__ unsigned ws[4];
    int b = blockIdx.x;
    int t = threadIdx.x;
    int wave = t >> 6, lane = t & 63;
    int bb = bucketbase[b], be = bucketbase[b + 1];
    c[t] = 0u;
    __syncthreads();
    for (int i = bb + t; i < be; i += 256)
        atomicAdd(&c[(unsigned)(bpack[i] >> 32) & 255u], 1u);
    __syncthreads();
    unsigned own = c[t];
    unsigned val = own;
#pragma unroll
    for (int d = 1; d < 64; d <<= 1) {
        unsigned n = __shfl_up(val, d, 64);
        if (lane >= d) val += n;
    }
    if (lane == 63) ws[wave] = val;
    __syncthreads();
    if (t < 4) {
        unsigned wv = ws[t];
#pragma unroll
        for (int d = 1; d < 4; d <<= 1) {
            unsigned n = __shfl_up(wv, d, 64);
            if (t >= d) wv += n;
        }
        ws[t] = wv;
    }
    __syncthreads();
    unsigned excl = ((wave > 0) ? ws[wave - 1] : 0u) + val - own;
    int node = (b << 8) + t;
    if (node < N_NODES) rowptr[node] = bb + (int)excl;
    if (b == NBINS - 1 && t == 0) rowptr[N_NODES] = N_EDGES;
    __syncthreads();
    c[t] = excl;
    __syncthreads();
    for (int i = bb + t; i < be; i += 256) {
        unsigned long long p = bpack[i];
        unsigned slot = atomicAdd(&c[(unsigned)(p >> 32) & 255u], 1u);
        esrc[bb + (int)slot] = (int)(unsigned)p;
    }
}

// ---------------- mean aggregation: one wave/node, 2x unrolled -> 8 edges (2 VMEM) in flight ------
__global__ void k_aggregate(const unsigned short* __restrict__ feat,
                            const int* __restrict__ esrc,
                            const int* __restrict__ rowptr,
                            unsigned short* __restrict__ out) {
    int node = blockIdx.x * 4 + (threadIdx.x >> 6);
    if (node >= N_NODES) return;
    int lane = threadIdx.x & 63;
    int sub = lane >> 4;
    int fl = lane & 15;
    int s = rowptr[node], e = rowptr[node + 1];
    float a0[8], a1[8];
#pragma unroll
    for (int q = 0; q < 8; ++q) { a0[q] = 0.f; a1[q] = 0.f; }

    int j = s + sub;
    for (; j + 4 < e; j += 8) {
        int sv0 = esrc[j];
        int sv1 = esrc[j + 4];
        short8 v0 = *(const short8*)(feat + (size_t)sv0 * FDIM + fl * 8);
        short8 v1 = *(const short8*)(feat + (size_t)sv1 * FDIM + fl * 8);
#pragma unroll
        for (int q = 0; q < 8; ++q) {
            a0[q] += bf2f((unsigned short)v0[q]);
            a1[q] += bf2f((unsigned short)v1[q]);
        }
    }
    if (j < e) {
        int sv = esrc[j];
        short8 v = *(const short8*)(feat + (size_t)sv * FDIM + fl * 8);
#pragma unroll
        for (int q = 0; q < 8; ++q) a0[q] += bf2f((unsigned short)v[q]);
    }
#pragma unroll
    for (int q = 0; q < 8; ++q) a0[q] += a1[q];
#pragma unroll
    for (int q = 0; q < 8; ++q) {
        a0[q] += __shfl_xor(a0[q], 16, 64);
        a0[q] += __shfl_xor(a0[q], 32, 64);
    }
    int deg = e - s;
    float inv = 1.0f / (float)(deg > 1 ? deg : 1);
    if (sub == 0) {
        short8 o;
#pragma unroll
        for (int q = 0; q < 8; ++q) o[q] = (short)f2bf(a0[q] * inv);
        *(short8*)(out + (size_t)node * FDIM + fl * 8) = o;
    }
}

// ---------------- layer-1 GEMM: out = relu([A0 | A1] @ W + bias), bf16 out ----------------
__global__ __launch_bounds__(256) void k_gemm_layer(
        const unsigned short* __restrict__ A0, const unsigned short* __restrict__ A1,
        const unsigned short* __restrict__ Bp, const float* __restrict__ bias,
        unsigned short* __restrict__ out) {
    int wave = threadIdx.x >> 6;
    int lane = threadIdx.x & 63;
    int rowblk = blockIdx.x * 64 + wave * 16;
    int lrow = lane & 15;
    int kgrp = lane >> 4;
    int arow = rowblk + lrow; if (arow > N_NODES - 1) arow = N_NODES - 1;

    f32x4 acc[8];
#pragma unroll
    for (int c = 0; c < 8; ++c) acc[c] = (f32x4){0.f, 0.f, 0.f, 0.f};

#pragma unroll
    for (int kb = 0; kb < 8; ++kb) {
        const unsigned short* Asrc = (kb < 4) ? A0 : A1;
        int kk = (kb & 3) * 32 + kgrp * 8;
        short8 a = *(const short8*)(Asrc + (size_t)arow * FDIM + kk);
        int k8 = kb * 4 + kgrp;
        const unsigned short* brow = Bp + ((size_t)k8 * FDIM + lrow) * 8;
#pragma unroll
        for (int c = 0; c < 8; ++c) {
            short8 b = *(const short8*)(brow + c * 16 * 8);
            acc[c] = __builtin_amdgcn_mfma_f32_16x16x32_bf16(a, b, acc[c], 0, 0, 0);
        }
    }

    int orowbase = rowblk + kgrp * 4;
#pragma unroll
    for (int c = 0; c < 8; ++c) {
        int col = c * 16 + lrow;
        float bv = bias[col];
#pragma unroll
        for (int i = 0; i < 4; ++i) {
            int r = orowbase + i;
            if (r < N_NODES) {
                float v = acc[c][i] + bv;
                v = fmaxf(v, 0.f);
                out[(size_t)r * FDIM + col] = f2bf(v);
            }
        }
    }
}

// ---------------- final: layer-2 GEMM + relu -> LDS -> head GEMM -> fp32 out ----------------
__global__ __launch_bounds__(256) void k_gemm_final(
        const unsigned short* __restrict__ A0, const unsigned short* __restrict__ A1,
        const unsigned short* __restrict__ Bp, const float* __restrict__ bias,
        const unsigned short* __restrict__ Bp3, const float* __restrict__ bias3,
        float* __restrict__ out) {
    __shared__ unsigned short Alds[4][16][LPAD];
    int wave = threadIdx.x >> 6;
    int lane = threadIdx.x & 63;
    int rowblk = blockIdx.x * 64 + wave * 16;
    int lrow = lane & 15;
    int kgrp = lane >> 4;
    int arow = rowblk + lrow; if (arow > N_NODES - 1) arow = N_NODES - 1;

    f32x4 acc2[8];
#pragma unroll
    for (int c = 0; c < 8; ++c) acc2[c] = (f32x4){0.f, 0.f, 0.f, 0.f};

#pragma unroll
    for (int kb = 0; kb < 8; ++kb) {
        const unsigned short* Asrc = (kb < 4) ? A0 : A1;
        int kk = (kb & 3) * 32 + kgrp * 8;
        short8 a = *(const short8*)(Asrc + (size_t)arow * FDIM + kk);
        int k8 = kb * 4 + kgrp;
        const unsigned short* brow = Bp + ((size_t)k8 * FDIM + lrow) * 8;
#pragma unroll
        for (int c = 0; c < 8; ++c) {
            short8 b = *(const short8*)(brow + c * 16 * 8);
            acc2[c] = __builtin_amdgcn_mfma_f32_16x16x32_bf16(a, b, acc2[c], 0, 0, 0);
        }
    }

    int srowbase = kgrp * 4;
#pragma unroll
    for (int c = 0; c < 8; ++c) {
        int col = c * 16 + lrow;
        float bv = bias[col];
#pragma unroll
        for (int i = 0; i < 4; ++i) {
            float v = acc2[c][i] + bv;
            v = fmaxf(v, 0.f);
            Alds[wave][srowbase + i][col] = f2bf(v);
        }
    }

    f32x4 acc3[3];
#pragma unroll
    for (int c = 0; c < 3; ++c) acc3[c] = (f32x4){0.f, 0.f, 0.f, 0.f};

#pragma unroll
    for (int kb = 0; kb < 4; ++kb) {
        short8 a = *(const short8*)(&Alds[wave][lrow][kb * 32 + kgrp * 8]);
        int k8 = kb * 4 + kgrp;
        const unsigned short* brow = Bp3 + ((size_t)k8 * NCLS_PAD + lrow) * 8;
#pragma unroll
        for (int c = 0; c < 3; ++c) {
            short8 b = *(const short8*)(brow + c * 16 * 8);
            acc3[c] = __builtin_amdgcn_mfma_f32_16x16x32_bf16(a, b, acc3[c], 0, 0, 0);
        }
    }

    int orowbase = rowblk + kgrp * 4;
#pragma unroll
    for (int c = 0; c < 3; ++c) {
        int col = c * 16 + lrow;
        if (col < NCLS) {
            float bv = bias3[col];
#pragma unroll
            for (int i = 0; i < 4; ++i) {
                int r = orowbase + i;
                if (r < N_NODES)
                    out[(size_t)r * NCLS + col] = acc3[c][i] + bv;
            }
        }
    }
}

extern "C" void kernel_launch(void* const* d_in, const int* in_sizes, int n_in,
                              void* d_out, int out_size, void* d_ws, size_t ws_size,
                              hipStream_t stream) {
    const float* x    = (const float*)d_in[0];
    const int*   ei   = (const int*)d_in[1];
    const float* W1l  = (const float*)d_in[2];
    const float* W1r  = (const float*)d_in[3];
    const float* b1   = (const float*)d_in[4];
    const float* W2l  = (const float*)d_in[5];
    const float* W2r  = (const float*)d_in[6];
    const float* b2   = (const float*)d_in[7];
    const float* Wout = (const float*)d_in[8];
    const float* bout = (const float*)d_in[9];
    const int* src = ei;
    const int* dst = ei + N_EDGES;

    char* ws = (char*)d_ws;
    size_t off = 0;
    auto alloc = [&](size_t bytes) -> void* {
        void* p = ws + off;
        off += (bytes + 255) & ~(size_t)255;
        return p;
    };
    unsigned short* xb   = (unsigned short*)alloc((size_t)N_NODES * FDIM * 2);
    unsigned short* aggn = (unsigned short*)alloc((size_t)N_NODES * FDIM * 2);
    unsigned short* h1   = (unsigned short*)alloc((size_t)N_NODES * FDIM * 2);
    unsigned short* Bp1  = (unsigned short*)alloc((size_t)FDIM * 256 * 2);
    unsigned short* Bp2  = (unsigned short*)alloc((size_t)FDIM * 256 * 2);
    unsigned short* Bp3  = (unsigned short*)alloc((size_t)NCLS_PAD * FDIM * 2);
    float* b1p = (float*)alloc(FDIM * 4);
    float* b2p = (float*)alloc(FDIM * 4);
    float* b3p = (float*)alloc(NCLS_PAD * 4);
    int* rowptr    = (int*)alloc((size_t)(N_NODES + 1) * 4);
    int* esrc      = (int*)alloc((size_t)N_EDGES * 4);
    int* bh        = (int*)alloc((size_t)NBLKB * NBINS * 4);
    int* obh       = (int*)alloc((size_t)NBLKB * NBINS * 4);
    int* bucketbase= (int*)alloc((size_t)(NBINS + 1) * 4);
    unsigned* bsumB = (unsigned*)alloc((size_t)SCANB_NB * 4);
    unsigned long long* bpack = (unsigned long long*)alloc((size_t)N_EDGES * 8);

    // prologue: histogram | bf16 convert | weight packs (all independent)
    int proGrid = NBLKB + CVT_NB + PACK_NB;
    k_prologue<<<proGrid, 256, 0, stream>>>(
        dst, bh, (const float4*)x, (ushort4*)xb,
        W1l, W1r, b1, Bp1, b1p, W2l, W2r, b2, Bp2, b2p, Wout, bout, Bp3, b3p);

    // CSR build
    k_scanB1<<<SCANB_NB, 1024, 0, stream>>>(bh, obh, bsumB);
    k_scanB3<<<SCANB_NB, 1024, 0, stream>>>(obh, bsumB, bucketbase);
    k_binwriteB<<<NBLKB, 256, 0, stream>>>(src, dst, obh, bpack);
    k_bucket_csr<<<NBINS, 256, 0, stream>>>(bpack, bucketbase, rowptr, esrc);

    int aggGrid = (N_NODES + 3) / 4;
    int gemmGrid = (N_NODES + 63) / 64;

    // layer 1
    k_aggregate<<<aggGrid, 256, 0, stream>>>(xb, esrc, rowptr, aggn);
    k_gemm_layer<<<gemmGrid, 256, 0, stream>>>(aggn, xb, Bp1, b1p, h1);
    // layer 2 + head
    k_aggregate<<<aggGrid, 256, 0, stream>>>(h1, esrc, rowptr, aggn);
    k_gemm_final<<<gemmGrid, 256, 0, stream>>>(aggn, h1, Bp2, b2p, Bp3, b3p, (float*)d_out);
}

// Round 12
// 244.232 us; speedup vs baseline: 1.4465x; 1.0273x over previous
//
#include <hip/hip_runtime.h>
#include <hip/hip_bf16.h>

#define N_NODES 100000
#define N_EDGES 1600000
#define FDIM 128
#define NCLS 40
#define NCLS_PAD 48

#define NBINS ((N_NODES + 255) / 256)        // 391 buckets of 256 nodes
#define NBLKB 256                            // partition blocks (power of 2)
#define CHUNKB (N_EDGES / NBLKB)             // 6250 edges per block
#define SCANTOT (NBINS * NBLKB)              // 100096
#define SCANB_NB ((SCANTOT + 1023) / 1024)   // 98

#define LPAD 136                             // LDS row pad (272B row stride -> 2-way max, free)

#define PACK1 (FDIM * 256)
#define PACK2 (FDIM * 256)
#define PACK3 (NCLS_PAD * FDIM)
#define PACKTOT (PACK1 + PACK2 + PACK3)      // 71680
#define PACK_NB ((PACKTOT + 255) / 256)      // 280
#define CVT_N4 (N_NODES * FDIM / 4)          // 3.2M
#define CVT_NB ((CVT_N4 + 255) / 256)        // 12500

typedef __attribute__((ext_vector_type(8))) short short8;
typedef __attribute__((ext_vector_type(4))) float f32x4;

__device__ __forceinline__ float bf2f(unsigned short u) {
    union { unsigned int i; float f; } v; v.i = ((unsigned int)u) << 16; return v.f;
}
__device__ __forceinline__ unsigned short f2bf(float f) {
    __hip_bfloat16 h = __float2bfloat16(f);
    return *reinterpret_cast<unsigned short*>(&h);
}

// ---------------- merged weight pack helper ----------------
__device__ __forceinline__ void pack_one(const float* Wl, const float* Wr, const float* bin,
                                         unsigned short* Bp, float* bout,
                                         int ncols_out, int ncols_src, int Keach, int idx) {
    int K = (Wr != nullptr) ? 2 * Keach : Keach;
    int col = idx / K, k = idx % K;
    float v = 0.f;
    if (col < ncols_src)
        v = (k < Keach) ? Wl[(size_t)k * ncols_src + col]
                        : Wr[(size_t)(k - Keach) * ncols_src + col];
    Bp[((size_t)(k >> 3) * ncols_out + col) * 8 + (k & 7)] = f2bf(v);
    if (k == 0) bout[col] = (col < ncols_src) ? bin[col] : 0.f;
}

// ---------------- prologue: countB | cvt | pack, role by blockIdx ----------------
__global__ __launch_bounds__(256) void k_prologue(
        const int* __restrict__ dst, int* __restrict__ bh,
        const float4* __restrict__ x4, ushort4* __restrict__ xb4,
        const float* __restrict__ W1l, const float* __restrict__ W1r,
        const float* __restrict__ b1, unsigned short* __restrict__ Bp1, float* __restrict__ b1p,
        const float* __restrict__ W2l, const float* __restrict__ W2r,
        const float* __restrict__ b2, unsigned short* __restrict__ Bp2, float* __restrict__ b2p,
        const float* __restrict__ Wout, const float* __restrict__ bo,
        unsigned short* __restrict__ Bp3, float* __restrict__ b3p) {
    __shared__ unsigned h[NBINS];
    int b = blockIdx.x;
    if (b < NBLKB) {
        for (int r = threadIdx.x; r < NBINS; r += 256) h[r] = 0u;
        __syncthreads();
        int base = b * CHUNKB;
        int end = base + CHUNKB; if (end > N_EDGES) end = N_EDGES;
        for (int e = base + threadIdx.x; e < end; e += 256)
            atomicAdd(&h[dst[e] >> 8], 1u);
        __syncthreads();
        for (int r = threadIdx.x; r < NBINS; r += 256)
            bh[b * NBINS + r] = (int)h[r];
        return;
    }
    b -= NBLKB;
    if (b < CVT_NB) {
        int i = b * 256 + threadIdx.x;
        if (i < CVT_N4) {
            float4 v = x4[i];
            ushort4 o;
            o.x = f2bf(v.x); o.y = f2bf(v.y); o.z = f2bf(v.z); o.w = f2bf(v.w);
            xb4[i] = o;
        }
        return;
    }
    b -= CVT_NB;
    int idx = b * 256 + threadIdx.x;
    if (idx < PACK1) { pack_one(W1l, W1r, b1, Bp1, b1p, FDIM, FDIM, FDIM, idx); return; }
    idx -= PACK1;
    if (idx < PACK2) { pack_one(W2l, W2r, b2, Bp2, b2p, FDIM, FDIM, FDIM, idx); return; }
    idx -= PACK2;
    if (idx < PACK3) { pack_one(Wout, nullptr, bo, Bp3, b3p, NCLS_PAD, NCLS, FDIM, idx); }
}

// ---------------- radix scan phase 1: shfl-based local scan ----------------
// element g (bucket-major): r = g >> 8, b = g & 255 -> bh[b*NBINS+r]
__global__ __launch_bounds__(1024) void k_scanB1(const int* __restrict__ bh,
                                                 int* __restrict__ obh,
                                                 unsigned* __restrict__ bsumB) {
    __shared__ unsigned wsums[16];
    int t = threadIdx.x;
    int wave = t >> 6, lane = t & 63;
    int g = blockIdx.x * 1024 + t;
    unsigned v = 0u;
    int r = g >> 8, b = g & (NBLKB - 1);
    if (g < SCANTOT) v = (unsigned)bh[b * NBINS + r];
    unsigned val = v;
#pragma unroll
    for (int d = 1; d < 64; d <<= 1) {
        unsigned n = __shfl_up(val, d, 64);
        if (lane >= d) val += n;
    }
    if (lane == 63) wsums[wave] = val;
    __syncthreads();
    if (t < 16) {
        unsigned wv = wsums[t];
#pragma unroll
        for (int d = 1; d < 16; d <<= 1) {
            unsigned n = __shfl_up(wv, d, 64);
            if (t >= d) wv += n;
        }
        wsums[t] = wv;
    }
    __syncthreads();
    unsigned waveoff = (wave > 0) ? wsums[wave - 1] : 0u;
    if (g < SCANTOT) obh[b * NBINS + r] = (int)(waveoff + val - v);
    if (t == 1023) bsumB[blockIdx.x] = wsums[15];
}

// ---------------- radix scan phase 2 (merged): each block re-derives block offsets ----------------
__global__ __launch_bounds__(1024) void k_scanB3(int* __restrict__ obh,
                                                 const unsigned* __restrict__ bsumB,
                                                 int* __restrict__ bucketbase) {
    __shared__ unsigned soff[SCANB_NB];
    int t = threadIdx.x;
    if (t < SCANB_NB) soff[t] = bsumB[t];
    __syncthreads();
    if (t == 0) {
        unsigned run = 0;
        for (int i = 0; i < SCANB_NB; ++i) { unsigned v = soff[i]; soff[i] = run; run += v; }
    }
    __syncthreads();
    int g = blockIdx.x * 1024 + t;
    if (g < SCANTOT) {
        int r = g >> 8, b = g & (NBLKB - 1);
        int val = obh[b * NBINS + r] + (int)soff[blockIdx.x];
        obh[b * NBINS + r] = val;
        if (b == 0) bucketbase[r] = val;
    }
    if (g == 0) bucketbase[NBINS] = N_EDGES;
}

// ---------------- radix phase 3: scatter packed u32 (dstLocal<<24 | src) ----------------
__global__ __launch_bounds__(256) void k_binwriteB(const int* __restrict__ src, const int* __restrict__ dst,
                                                   const int* __restrict__ obh,
                                                   unsigned* __restrict__ bpack) {
    __shared__ unsigned pos[NBINS];
    for (int r = threadIdx.x; r < NBINS; r += 256)
        pos[r] = (unsigned)obh[blockIdx.x * NBINS + r];
    __syncthreads();
    int base = blockIdx.x * CHUNKB;
    int end = base + CHUNKB; if (end > N_EDGES) end = N_EDGES;
    for (int e = base + threadIdx.x; e < end; e += 256) {
        int d = dst[e];
        unsigned p = atomicAdd(&pos[d >> 8], 1u);
        bpack[p] = ((unsigned)(d & 255) << 24) | (unsigned)src[e];
    }
}

// ---------------- radix phase 4: per-bucket in-LDS CSR (shfl scan) ----------------
__global__ __launch_bounds__(256) void k_bucket_csr(const unsigned* __restrict__ bpack,
                                                    const int* __restrict__ bucketbase,
                                                    int* __restrict__ rowptr,
                                                    int* __restrict__ esrc) {
    __shared__ unsigned c[256];
    __shared__ unsigned ws[4];
    int b = blockIdx.x;
    int t = threadIdx.x;
    int wave = t >> 6, lane = t & 63;
    int bb = bucketbase[b], be = bucketbase[b + 1];
    c[t] = 0u;
    __syncthreads();
    for (int i = bb + t; i < be; i += 256)
        atomicAdd(&c[bpack[i] >> 24], 1u);
    __syncthreads();
    unsigned own = c[t];
    unsigned val = own;
#pragma unroll
    for (int d = 1; d < 64; d <<= 1) {
        unsigned n = __shfl_up(val, d, 64);
        if (lane >= d) val += n;
    }
    if (lane == 63) ws[wave] = val;
    __syncthreads();
    if (t < 4) {
        unsigned wv = ws[t];
#pragma unroll
        for (int d = 1; d < 4; d <<= 1) {
            unsigned n = __shfl_up(wv, d, 64);
            if (t >= d) wv += n;
        }
        ws[t] = wv;
    }
    __syncthreads();
    unsigned excl = ((wave > 0) ? ws[wave - 1] : 0u) + val - own;
    int node = (b << 8) + t;
    if (node < N_NODES) rowptr[node] = bb + (int)excl;
    if (b == NBINS - 1 && t == 0) rowptr[N_NODES] = N_EDGES;
    __syncthreads();
    c[t] = excl;
    __syncthreads();
    for (int i = bb + t; i < be; i += 256) {
        unsigned p = bpack[i];
        unsigned slot = atomicAdd(&c[p >> 24], 1u);
        esrc[bb + (int)slot] = (int)(p & 0x00FFFFFFu);
    }
}

// ---------------- mean aggregation: one wave/node, 4x unrolled -> 4 VMEM in flight ----------------
__global__ void k_aggregate(const unsigned short* __restrict__ feat,
                            const int* __restrict__ esrc,
                            const int* __restrict__ rowptr,
                            unsigned short* __restrict__ out) {
    int node = blockIdx.x * 4 + (threadIdx.x >> 6);
    if (node >= N_NODES) return;
    int lane = threadIdx.x & 63;
    int sub = lane >> 4;
    int fl = lane & 15;
    int s = rowptr[node], e = rowptr[node + 1];
    float a0[8], a1[8], a2[8], a3[8];
#pragma unroll
    for (int q = 0; q < 8; ++q) { a0[q] = 0.f; a1[q] = 0.f; a2[q] = 0.f; a3[q] = 0.f; }

    int j = s + sub;
    for (; j + 12 < e; j += 16) {
        int sv0 = esrc[j];
        int sv1 = esrc[j + 4];
        int sv2 = esrc[j + 8];
        int sv3 = esrc[j + 12];
        short8 v0 = *(const short8*)(feat + (size_t)sv0 * FDIM + fl * 8);
        short8 v1 = *(const short8*)(feat + (size_t)sv1 * FDIM + fl * 8);
        short8 v2 = *(const short8*)(feat + (size_t)sv2 * FDIM + fl * 8);
        short8 v3 = *(const short8*)(feat + (size_t)sv3 * FDIM + fl * 8);
#pragma unroll
        for (int q = 0; q < 8; ++q) {
            a0[q] += bf2f((unsigned short)v0[q]);
            a1[q] += bf2f((unsigned short)v1[q]);
            a2[q] += bf2f((unsigned short)v2[q]);
            a3[q] += bf2f((unsigned short)v3[q]);
        }
    }
    for (; j + 4 < e; j += 8) {
        int sv0 = esrc[j];
        int sv1 = esrc[j + 4];
        short8 v0 = *(const short8*)(feat + (size_t)sv0 * FDIM + fl * 8);
        short8 v1 = *(const short8*)(feat + (size_t)sv1 * FDIM + fl * 8);
#pragma unroll
        for (int q = 0; q < 8; ++q) {
            a0[q] += bf2f((unsigned short)v0[q]);
            a1[q] += bf2f((unsigned short)v1[q]);
        }
    }
    if (j < e) {
        int sv = esrc[j];
        short8 v = *(const short8*)(feat + (size_t)sv * FDIM + fl * 8);
#pragma unroll
        for (int q = 0; q < 8; ++q) a0[q] += bf2f((unsigned short)v[q]);
    }
#pragma unroll
    for (int q = 0; q < 8; ++q) a0[q] += (a1[q] + a2[q]) + a3[q];
#pragma unroll
    for (int q = 0; q < 8; ++q) {
        a0[q] += __shfl_xor(a0[q], 16, 64);
        a0[q] += __shfl_xor(a0[q], 32, 64);
    }
    int deg = e - s;
    float inv = 1.0f / (float)(deg > 1 ? deg : 1);
    if (sub == 0) {
        short8 o;
#pragma unroll
        for (int q = 0; q < 8; ++q) o[q] = (short)f2bf(a0[q] * inv);
        *(short8*)(out + (size_t)node * FDIM + fl * 8) = o;
    }
}

// ---------------- layer-1 GEMM: out = relu([A0 | A1] @ W + bias), bf16 out ----------------
__global__ __launch_bounds__(256) void k_gemm_layer(
        const unsigned short* __restrict__ A0, const unsigned short* __restrict__ A1,
        const unsigned short* __restrict__ Bp, const float* __restrict__ bias,
        unsigned short* __restrict__ out) {
    int wave = threadIdx.x >> 6;
    int lane = threadIdx.x & 63;
    int rowblk = blockIdx.x * 64 + wave * 16;
    int lrow = lane & 15;
    int kgrp = lane >> 4;
    int arow = rowblk + lrow; if (arow > N_NODES - 1) arow = N_NODES - 1;

    f32x4 acc[8];
#pragma unroll
    for (int c = 0; c < 8; ++c) acc[c] = (f32x4){0.f, 0.f, 0.f, 0.f};

#pragma unroll
    for (int kb = 0; kb < 8; ++kb) {
        const unsigned short* Asrc = (kb < 4) ? A0 : A1;
        int kk = (kb & 3) * 32 + kgrp * 8;
        short8 a = *(const short8*)(Asrc + (size_t)arow * FDIM + kk);
        int k8 = kb * 4 + kgrp;
        const unsigned short* brow = Bp + ((size_t)k8 * FDIM + lrow) * 8;
#pragma unroll
        for (int c = 0; c < 8; ++c) {
            short8 b = *(const short8*)(brow + c * 16 * 8);
            acc[c] = __builtin_amdgcn_mfma_f32_16x16x32_bf16(a, b, acc[c], 0, 0, 0);
        }
    }

    int orowbase = rowblk + kgrp * 4;
#pragma unroll
    for (int c = 0; c < 8; ++c) {
        int col = c * 16 + lrow;
        float bv = bias[col];
#pragma unroll
        for (int i = 0; i < 4; ++i) {
            int r = orowbase + i;
            if (r < N_NODES) {
                float v = acc[c][i] + bv;
                v = fmaxf(v, 0.f);
                out[(size_t)r * FDIM + col] = f2bf(v);
            }
        }
    }
}

// ---------------- final: layer-2 GEMM + relu -> LDS -> head GEMM -> fp32 out ----------------
__global__ __launch_bounds__(256) void k_gemm_final(
        const unsigned short* __restrict__ A0, const unsigned short* __restrict__ A1,
        const unsigned short* __restrict__ Bp, const float* __restrict__ bias,
        const unsigned short* __restrict__ Bp3, const float* __restrict__ bias3,
        float* __restrict__ out) {
    __shared__ unsigned short Alds[4][16][LPAD];
    int wave = threadIdx.x >> 6;
    int lane = threadIdx.x & 63;
    int rowblk = blockIdx.x * 64 + wave * 16;
    int lrow = lane & 15;
    int kgrp = lane >> 4;
    int arow = rowblk + lrow; if (arow > N_NODES - 1) arow = N_NODES - 1;

    f32x4 acc2[8];
#pragma unroll
    for (int c = 0; c < 8; ++c) acc2[c] = (f32x4){0.f, 0.f, 0.f, 0.f};

#pragma unroll
    for (int kb = 0; kb < 8; ++kb) {
        const unsigned short* Asrc = (kb < 4) ? A0 : A1;
        int kk = (kb & 3) * 32 + kgrp * 8;
        short8 a = *(const short8*)(Asrc + (size_t)arow * FDIM + kk);
        int k8 = kb * 4 + kgrp;
        const unsigned short* brow = Bp + ((size_t)k8 * FDIM + lrow) * 8;
#pragma unroll
        for (int c = 0; c < 8; ++c) {
            short8 b = *(const short8*)(brow + c * 16 * 8);
            acc2[c] = __builtin_amdgcn_mfma_f32_16x16x32_bf16(a, b, acc2[c], 0, 0, 0);
        }
    }

    int srowbase = kgrp * 4;
#pragma unroll
    for (int c = 0; c < 8; ++c) {
        int col = c * 16 + lrow;
        float bv = bias[col];
#pragma unroll
        for (int i = 0; i < 4; ++i) {
            float v = acc2[c][i] + bv;
            v = fmaxf(v, 0.f);
            Alds[wave][srowbase + i][col] = f2bf(v);
        }
    }

    f32x4 acc3[3];
#pragma unroll
    for (int c = 0; c < 3; ++c) acc3[c] = (f32x4){0.f, 0.f, 0.f, 0.f};

#pragma unroll
    for (int kb = 0; kb < 4; ++kb) {
        short8 a = *(const short8*)(&Alds[wave][lrow][kb * 32 + kgrp * 8]);
        int k8 = kb * 4 + kgrp;
        const unsigned short* brow = Bp3 + ((size_t)k8 * NCLS_PAD + lrow) * 8;
#pragma unroll
        for (int c = 0; c < 3; ++c) {
            short8 b = *(const short8*)(brow + c * 16 * 8);
            acc3[c] = __builtin_amdgcn_mfma_f32_16x16x32_bf16(a, b, acc3[c], 0, 0, 0);
        }
    }

    int orowbase = rowblk + kgrp * 4;
#pragma unroll
    for (int c = 0; c < 3; ++c) {
        int col = c * 16 + lrow;
        if (col < NCLS) {
            float bv = bias3[col];
#pragma unroll
            for (int i = 0; i < 4; ++i) {
                int r = orowbase + i;
                if (r < N_NODES)
                    out[(size_t)r * NCLS + col] = acc3[c][i] + bv;
            }
        }
    }
}

extern "C" void kernel_launch(void* const* d_in, const int* in_sizes, int n_in,
                              void* d_out, int out_size, void* d_ws, size_t ws_size,
                              hipStream_t stream) {
    const float* x    = (const float*)d_in[0];
    const int*   ei   = (const int*)d_in[1];
    const float* W1l  = (const float*)d_in[2];
    const float* W1r  = (const float*)d_in[3];
    const float* b1   = (const float*)d_in[4];
    const float* W2l  = (const float*)d_in[5];
    const float* W2r  = (const float*)d_in[6];
    const float* b2   = (const float*)d_in[7];
    const float* Wout = (const float*)d_in[8];
    const float* bout = (const float*)d_in[9];
    const int* src = ei;
    const int* dst = ei + N_EDGES;

    char* ws = (char*)d_ws;
    size_t off = 0;
    auto alloc = [&](size_t bytes) -> void* {
        void* p = ws + off;
        off += (bytes + 255) & ~(size_t)255;
        return p;
    };
    unsigned short* xb   = (unsigned short*)alloc((size_t)N_NODES * FDIM * 2);
    unsigned short* aggn = (unsigned short*)alloc((size_t)N_NODES * FDIM * 2);
    unsigned short* h1   = (unsigned short*)alloc((size_t)N_NODES * FDIM * 2);
    unsigned short* Bp1  = (unsigned short*)alloc((size_t)FDIM * 256 * 2);
    unsigned short* Bp2  = (unsigned short*)alloc((size_t)FDIM * 256 * 2);
    unsigned short* Bp3  = (unsigned short*)alloc((size_t)NCLS_PAD * FDIM * 2);
    float* b1p = (float*)alloc(FDIM * 4);
    float* b2p = (float*)alloc(FDIM * 4);
    float* b3p = (float*)alloc(NCLS_PAD * 4);
    int* rowptr    = (int*)alloc((size_t)(N_NODES + 1) * 4);
    int* esrc      = (int*)alloc((size_t)N_EDGES * 4);
    int* bh        = (int*)alloc((size_t)NBLKB * NBINS * 4);
    int* obh       = (int*)alloc((size_t)NBLKB * NBINS * 4);
    int* bucketbase= (int*)alloc((size_t)(NBINS + 1) * 4);
    unsigned* bsumB = (unsigned*)alloc((size_t)SCANB_NB * 4);
    unsigned* bpack = (unsigned*)alloc((size_t)N_EDGES * 4);

    // prologue: histogram | bf16 convert | weight packs (all independent)
    int proGrid = NBLKB + CVT_NB + PACK_NB;
    k_prologue<<<proGrid, 256, 0, stream>>>(
        dst, bh, (const float4*)x, (ushort4*)xb,
        W1l, W1r, b1, Bp1, b1p, W2l, W2r, b2, Bp2, b2p, Wout, bout, Bp3, b3p);

    // CSR build
    k_scanB1<<<SCANB_NB, 1024, 0, stream>>>(bh, obh, bsumB);
    k_scanB3<<<SCANB_NB, 1024, 0, stream>>>(obh, bsumB, bucketbase);
    k_binwriteB<<<NBLKB, 256, 0, stream>>>(src, dst, obh, bpack);
    k_bucket_csr<<<NBINS, 256, 0, stream>>>(bpack, bucketbase, rowptr, esrc);

    int aggGrid = (N_NODES + 3) / 4;
    int gemmGrid = (N_NODES + 63) / 64;

    // layer 1
    k_aggregate<<<aggGrid, 256, 0, stream>>>(xb, esrc, rowptr, aggn);
    k_gemm_layer<<<gemmGrid, 256, 0, stream>>>(aggn, xb, Bp1, b1p, h1);
    // layer 2 + head
    k_aggregate<<<aggGrid, 256, 0, stream>>>(h1, esrc, rowptr, aggn);
    k_gemm_final<<<gemmGrid, 256, 0, stream>>>(aggn, h1, Bp2, b2p, Bp3, b3p, (float*)d_out);
}

// Round 13
// 234.362 us; speedup vs baseline: 1.5074x; 1.0421x over previous
//
#include <hip/hip_runtime.h>
#include <hip/hip_bf16.h>

#define N_NODES 100000
#define N_EDGES 1600000
#define FDIM 128
#define NCLS 40
#define NCLS_PAD 48

#define NBINS ((N_NODES + 255) / 256)        // 391 buckets of 256 nodes
#define NBLKB 256                            // partition blocks (power of 2)
#define CHUNKB (N_EDGES / NBLKB)             // 6250 edges per block
#define SCANTOT (NBINS * NBLKB)              // 100096
#define SCANB_NB ((SCANTOT + 1023) / 1024)   // 98

#define LPAD 136                             // LDS row pad (272B row stride -> 2-way max, free)

#define PACK1 (FDIM * 256)
#define PACK2 (FDIM * 256)
#define PACK3 (NCLS_PAD * FDIM)
#define PACKTOT (PACK1 + PACK2 + PACK3)      // 71680
#define PACK_NB ((PACKTOT + 255) / 256)      // 280
#define CVT_N4 (N_NODES * FDIM / 4)          // 3.2M
#define CVT_NB ((CVT_N4 + 255) / 256)        // 12500

typedef __attribute__((ext_vector_type(8))) short short8;
typedef __attribute__((ext_vector_type(4))) float f32x4;

__device__ __forceinline__ float bf2f(unsigned short u) {
    union { unsigned int i; float f; } v; v.i = ((unsigned int)u) << 16; return v.f;
}
__device__ __forceinline__ unsigned short f2bf(float f) {
    __hip_bfloat16 h = __float2bfloat16(f);
    return *reinterpret_cast<unsigned short*>(&h);
}

// ---------------- merged weight pack helper ----------------
__device__ __forceinline__ void pack_one(const float* Wl, const float* Wr, const float* bin,
                                         unsigned short* Bp, float* bout,
                                         int ncols_out, int ncols_src, int Keach, int idx) {
    int K = (Wr != nullptr) ? 2 * Keach : Keach;
    int col = idx / K, k = idx % K;
    float v = 0.f;
    if (col < ncols_src)
        v = (k < Keach) ? Wl[(size_t)k * ncols_src + col]
                        : Wr[(size_t)(k - Keach) * ncols_src + col];
    Bp[((size_t)(k >> 3) * ncols_out + col) * 8 + (k & 7)] = f2bf(v);
    if (k == 0) bout[col] = (col < ncols_src) ? bin[col] : 0.f;
}

// ---------------- prologue: countB | cvt | pack, role by blockIdx ----------------
__global__ __launch_bounds__(256) void k_prologue(
        const int* __restrict__ dst, int* __restrict__ bh,
        const float4* __restrict__ x4, ushort4* __restrict__ xb4,
        const float* __restrict__ W1l, const float* __restrict__ W1r,
        const float* __restrict__ b1, unsigned short* __restrict__ Bp1, float* __restrict__ b1p,
        const float* __restrict__ W2l, const float* __restrict__ W2r,
        const float* __restrict__ b2, unsigned short* __restrict__ Bp2, float* __restrict__ b2p,
        const float* __restrict__ Wout, const float* __restrict__ bo,
        unsigned short* __restrict__ Bp3, float* __restrict__ b3p) {
    __shared__ unsigned h[NBINS];
    int b = blockIdx.x;
    if (b < NBLKB) {
        for (int r = threadIdx.x; r < NBINS; r += 256) h[r] = 0u;
        __syncthreads();
        int base = b * CHUNKB;
        int end = base + CHUNKB; if (end > N_EDGES) end = N_EDGES;
        for (int e = base + threadIdx.x; e < end; e += 256)
            atomicAdd(&h[dst[e] >> 8], 1u);
        __syncthreads();
        for (int r = threadIdx.x; r < NBINS; r += 256)
            bh[b * NBINS + r] = (int)h[r];
        return;
    }
    b -= NBLKB;
    if (b < CVT_NB) {
        int i = b * 256 + threadIdx.x;
        if (i < CVT_N4) {
            float4 v = x4[i];
            ushort4 o;
            o.x = f2bf(v.x); o.y = f2bf(v.y); o.z = f2bf(v.z); o.w = f2bf(v.w);
            xb4[i] = o;
        }
        return;
    }
    b -= CVT_NB;
    int idx = b * 256 + threadIdx.x;
    if (idx < PACK1) { pack_one(W1l, W1r, b1, Bp1, b1p, FDIM, FDIM, FDIM, idx); return; }
    idx -= PACK1;
    if (idx < PACK2) { pack_one(W2l, W2r, b2, Bp2, b2p, FDIM, FDIM, FDIM, idx); return; }
    idx -= PACK2;
    if (idx < PACK3) { pack_one(Wout, nullptr, bo, Bp3, b3p, NCLS_PAD, NCLS, FDIM, idx); }
}

// ---------------- radix scan phase 1: shfl-based local scan ----------------
// element g (bucket-major): r = g >> 8, b = g & 255 -> bh[b*NBINS+r]
__global__ __launch_bounds__(1024) void k_scanB1(const int* __restrict__ bh,
                                                 int* __restrict__ obh,
                                                 unsigned* __restrict__ bsumB) {
    __shared__ unsigned wsums[16];
    int t = threadIdx.x;
    int wave = t >> 6, lane = t & 63;
    int g = blockIdx.x * 1024 + t;
    unsigned v = 0u;
    int r = g >> 8, b = g & (NBLKB - 1);
    if (g < SCANTOT) v = (unsigned)bh[b * NBINS + r];
    unsigned val = v;
#pragma unroll
    for (int d = 1; d < 64; d <<= 1) {
        unsigned n = __shfl_up(val, d, 64);
        if (lane >= d) val += n;
    }
    if (lane == 63) wsums[wave] = val;
    __syncthreads();
    if (t < 16) {
        unsigned wv = wsums[t];
#pragma unroll
        for (int d = 1; d < 16; d <<= 1) {
            unsigned n = __shfl_up(wv, d, 64);
            if (t >= d) wv += n;
        }
        wsums[t] = wv;
    }
    __syncthreads();
    unsigned waveoff = (wave > 0) ? wsums[wave - 1] : 0u;
    if (g < SCANTOT) obh[b * NBINS + r] = (int)(waveoff + val - v);
    if (t == 1023) bsumB[blockIdx.x] = wsums[15];
}

// ---------------- radix scan phase 2 (merged): each block re-derives block offsets ----------------
__global__ __launch_bounds__(1024) void k_scanB3(int* __restrict__ obh,
                                                 const unsigned* __restrict__ bsumB,
                                                 int* __restrict__ bucketbase) {
    __shared__ unsigned soff[SCANB_NB];
    int t = threadIdx.x;
    if (t < SCANB_NB) soff[t] = bsumB[t];
    __syncthreads();
    if (t == 0) {
        unsigned run = 0;
        for (int i = 0; i < SCANB_NB; ++i) { unsigned v = soff[i]; soff[i] = run; run += v; }
    }
    __syncthreads();
    int g = blockIdx.x * 1024 + t;
    if (g < SCANTOT) {
        int r = g >> 8, b = g & (NBLKB - 1);
        int val = obh[b * NBINS + r] + (int)soff[blockIdx.x];
        obh[b * NBINS + r] = val;
        if (b == 0) bucketbase[r] = val;
    }
    if (g == 0) bucketbase[NBINS] = N_EDGES;
}

// ---------------- radix phase 3: scatter packed u32 (dstLocal<<24 | src) ----------------
__global__ __launch_bounds__(256) void k_binwriteB(const int* __restrict__ src, const int* __restrict__ dst,
                                                   const int* __restrict__ obh,
                                                   unsigned* __restrict__ bpack) {
    __shared__ unsigned pos[NBINS];
    for (int r = threadIdx.x; r < NBINS; r += 256)
        pos[r] = (unsigned)obh[blockIdx.x * NBINS + r];
    __syncthreads();
    int base = blockIdx.x * CHUNKB;
    int end = base + CHUNKB; if (end > N_EDGES) end = N_EDGES;
    for (int e = base + threadIdx.x; e < end; e += 256) {
        int d = dst[e];
        unsigned p = atomicAdd(&pos[d >> 8], 1u);
        bpack[p] = ((unsigned)(d & 255) << 24) | (unsigned)src[e];
    }
}

// ---------------- radix phase 4: per-bucket in-LDS CSR (shfl scan) ----------------
__global__ __launch_bounds__(256) void k_bucket_csr(const unsigned* __restrict__ bpack,
                                                    const int* __restrict__ bucketbase,
                                                    int* __restrict__ rowptr,
                                                    int* __restrict__ esrc) {
    __shared__ unsigned c[256];
    __shared__ unsigned ws[4];
    int b = blockIdx.x;
    int t = threadIdx.x;
    int wave = t >> 6, lane = t & 63;
    int bb = bucketbase[b], be = bucketbase[b + 1];
    c[t] = 0u;
    __syncthreads();
    for (int i = bb + t; i < be; i += 256)
        atomicAdd(&c[bpack[i] >> 24], 1u);
    __syncthreads();
    unsigned own = c[t];
    unsigned val = own;
#pragma unroll
    for (int d = 1; d < 64; d <<= 1) {
        unsigned n = __shfl_up(val, d, 64);
        if (lane >= d) val += n;
    }
    if (lane == 63) ws[wave] = val;
    __syncthreads();
    if (t < 4) {
        unsigned wv = ws[t];
#pragma unroll
        for (int d = 1; d < 4; d <<= 1) {
            unsigned n = __shfl_up(wv, d, 64);
            if (t >= d) wv += n;
        }
        ws[t] = wv;
    }
    __syncthreads();
    unsigned excl = ((wave > 0) ? ws[wave - 1] : 0u) + val - own;
    int node = (b << 8) + t;
    if (node < N_NODES) rowptr[node] = bb + (int)excl;
    if (b == NBINS - 1 && t == 0) rowptr[N_NODES] = N_EDGES;
    __syncthreads();
    c[t] = excl;
    __syncthreads();
    for (int i = bb + t; i < be; i += 256) {
        unsigned p = bpack[i];
        unsigned slot = atomicAdd(&c[p >> 24], 1u);
        esrc[bb + (int)slot] = (int)(p & 0x00FFFFFFu);
    }
}

// ---------------- mean aggregation: one wave/node, 2x unrolled (empirical sweet spot) ------------
// block=256: 4 nodes/block; VGPR ~24 keeps occupancy ~68%+. x4 unroll regressed (R12):
// mean degree 16 -> deep unroll rarely engages, only costs registers.
__global__ __launch_bounds__(256, 8) void k_aggregate(
                            const unsigned short* __restrict__ feat,
                            const int* __restrict__ esrc,
                            const int* __restrict__ rowptr,
                            unsigned short* __restrict__ out) {
    int node = blockIdx.x * 4 + (threadIdx.x >> 6);
    if (node >= N_NODES) return;
    int lane = threadIdx.x & 63;
    int sub = lane >> 4;
    int fl = lane & 15;
    int s = rowptr[node], e = rowptr[node + 1];
    float a0[8], a1[8];
#pragma unroll
    for (int q = 0; q < 8; ++q) { a0[q] = 0.f; a1[q] = 0.f; }

    int j = s + sub;
    for (; j + 4 < e; j += 8) {
        int sv0 = esrc[j];
        int sv1 = esrc[j + 4];
        short8 v0 = *(const short8*)(feat + (size_t)sv0 * FDIM + fl * 8);
        short8 v1 = *(const short8*)(feat + (size_t)sv1 * FDIM + fl * 8);
#pragma unroll
        for (int q = 0; q < 8; ++q) {
            a0[q] += bf2f((unsigned short)v0[q]);
            a1[q] += bf2f((unsigned short)v1[q]);
        }
    }
    if (j < e) {
        int sv = esrc[j];
        short8 v = *(const short8*)(feat + (size_t)sv * FDIM + fl * 8);
#pragma unroll
        for (int q = 0; q < 8; ++q) a0[q] += bf2f((unsigned short)v[q]);
    }
#pragma unroll
    for (int q = 0; q < 8; ++q) a0[q] += a1[q];
#pragma unroll
    for (int q = 0; q < 8; ++q) {
        a0[q] += __shfl_xor(a0[q], 16, 64);
        a0[q] += __shfl_xor(a0[q], 32, 64);
    }
    int deg = e - s;
    float inv = 1.0f / (float)(deg > 1 ? deg : 1);
    if (sub == 0) {
        short8 o;
#pragma unroll
        for (int q = 0; q < 8; ++q) o[q] = (short)f2bf(a0[q] * inv);
        *(short8*)(out + (size_t)node * FDIM + fl * 8) = o;
    }
}

// ---------------- layer-1 GEMM: out = relu([A0 | A1] @ W + bias), bf16 out ----------------
__global__ __launch_bounds__(256) void k_gemm_layer(
        const unsigned short* __restrict__ A0, const unsigned short* __restrict__ A1,
        const unsigned short* __restrict__ Bp, const float* __restrict__ bias,
        unsigned short* __restrict__ out) {
    int wave = threadIdx.x >> 6;
    int lane = threadIdx.x & 63;
    int rowblk = blockIdx.x * 64 + wave * 16;
    int lrow = lane & 15;
    int kgrp = lane >> 4;
    int arow = rowblk + lrow; if (arow > N_NODES - 1) arow = N_NODES - 1;

    f32x4 acc[8];
#pragma unroll
    for (int c = 0; c < 8; ++c) acc[c] = (f32x4){0.f, 0.f, 0.f, 0.f};

#pragma unroll
    for (int kb = 0; kb < 8; ++kb) {
        const unsigned short* Asrc = (kb < 4) ? A0 : A1;
        int kk = (kb & 3) * 32 + kgrp * 8;
        short8 a = *(const short8*)(Asrc + (size_t)arow * FDIM + kk);
        int k8 = kb * 4 + kgrp;
        const unsigned short* brow = Bp + ((size_t)k8 * FDIM + lrow) * 8;
#pragma unroll
        for (int c = 0; c < 8; ++c) {
            short8 b = *(const short8*)(brow + c * 16 * 8);
            acc[c] = __builtin_amdgcn_mfma_f32_16x16x32_bf16(a, b, acc[c], 0, 0, 0);
        }
    }

    int orowbase = rowblk + kgrp * 4;
#pragma unroll
    for (int c = 0; c < 8; ++c) {
        int col = c * 16 + lrow;
        float bv = bias[col];
#pragma unroll
        for (int i = 0; i < 4; ++i) {
            int r = orowbase + i;
            if (r < N_NODES) {
                float v = acc[c][i] + bv;
                v = fmaxf(v, 0.f);
                out[(size_t)r * FDIM + col] = f2bf(v);
            }
        }
    }
}

// ---------------- final: layer-2 GEMM + relu -> LDS -> head GEMM -> fp32 out ----------------
__global__ __launch_bounds__(256) void k_gemm_final(
        const unsigned short* __restrict__ A0, const unsigned short* __restrict__ A1,
        const unsigned short* __restrict__ Bp, const float* __restrict__ bias,
        const unsigned short* __restrict__ Bp3, const float* __restrict__ bias3,
        float* __restrict__ out) {
    __shared__ unsigned short Alds[4][16][LPAD];
    int wave = threadIdx.x >> 6;
    int lane = threadIdx.x & 63;
    int rowblk = blockIdx.x * 64 + wave * 16;
    int lrow = lane & 15;
    int kgrp = lane >> 4;
    int arow = rowblk + lrow; if (arow > N_NODES - 1) arow = N_NODES - 1;

    f32x4 acc2[8];
#pragma unroll
    for (int c = 0; c < 8; ++c) acc2[c] = (f32x4){0.f, 0.f, 0.f, 0.f};

#pragma unroll
    for (int kb = 0; kb < 8; ++kb) {
        const unsigned short* Asrc = (kb < 4) ? A0 : A1;
        int kk = (kb & 3) * 32 + kgrp * 8;
        short8 a = *(const short8*)(Asrc + (size_t)arow * FDIM + kk);
        int k8 = kb * 4 + kgrp;
        const unsigned short* brow = Bp + ((size_t)k8 * FDIM + lrow) * 8;
#pragma unroll
        for (int c = 0; c < 8; ++c) {
            short8 b = *(const short8*)(brow + c * 16 * 8);
            acc2[c] = __builtin_amdgcn_mfma_f32_16x16x32_bf16(a, b, acc2[c], 0, 0, 0);
        }
    }

    int srowbase = kgrp * 4;
#pragma unroll
    for (int c = 0; c < 8; ++c) {
        int col = c * 16 + lrow;
        float bv = bias[col];
#pragma unroll
        for (int i = 0; i < 4; ++i) {
            float v = acc2[c][i] + bv;
            v = fmaxf(v, 0.f);
            Alds[wave][srowbase + i][col] = f2bf(v);
        }
    }

    f32x4 acc3[3];
#pragma unroll
    for (int c = 0; c < 3; ++c) acc3[c] = (f32x4){0.f, 0.f, 0.f, 0.f};

#pragma unroll
    for (int kb = 0; kb < 4; ++kb) {
        short8 a = *(const short8*)(&Alds[wave][lrow][kb * 32 + kgrp * 8]);
        int k8 = kb * 4 + kgrp;
        const unsigned short* brow = Bp3 + ((size_t)k8 * NCLS_PAD + lrow) * 8;
#pragma unroll
        for (int c = 0; c < 3; ++c) {
            short8 b = *(const short8*)(brow + c * 16 * 8);
            acc3[c] = __builtin_amdgcn_mfma_f32_16x16x32_bf16(a, b, acc3[c], 0, 0, 0);
        }
    }

    int orowbase = rowblk + kgrp * 4;
#pragma unroll
    for (int c = 0; c < 3; ++c) {
        int col = c * 16 + lrow;
        if (col < NCLS) {
            float bv = bias3[col];
#pragma unroll
            for (int i = 0; i < 4; ++i) {
                int r = orowbase + i;
                if (r < N_NODES)
                    out[(size_t)r * NCLS + col] = acc3[c][i] + bv;
            }
        }
    }
}

extern "C" void kernel_launch(void* const* d_in, const int* in_sizes, int n_in,
                              void* d_out, int out_size, void* d_ws, size_t ws_size,
                              hipStream_t stream) {
    const float* x    = (const float*)d_in[0];
    const int*   ei   = (const int*)d_in[1];
    const float* W1l  = (const float*)d_in[2];
    const float* W1r  = (const float*)d_in[3];
    const float* b1   = (const float*)d_in[4];
    const float* W2l  = (const float*)d_in[5];
    const float* W2r  = (const float*)d_in[6];
    const float* b2   = (const float*)d_in[7];
    const float* Wout = (const float*)d_in[8];
    const float* bout = (const float*)d_in[9];
    const int* src = ei;
    const int* dst = ei + N_EDGES;

    char* ws = (char*)d_ws;
    size_t off = 0;
    auto alloc = [&](size_t bytes) -> void* {
        void* p = ws + off;
        off += (bytes + 255) & ~(size_t)255;
        return p;
    };
    unsigned short* xb   = (unsigned short*)alloc((size_t)N_NODES * FDIM * 2);
    unsigned short* aggn = (unsigned short*)alloc((size_t)N_NODES * FDIM * 2);
    unsigned short* h1   = (unsigned short*)alloc((size_t)N_NODES * FDIM * 2);
    unsigned short* Bp1  = (unsigned short*)alloc((size_t)FDIM * 256 * 2);
    unsigned short* Bp2  = (unsigned short*)alloc((size_t)FDIM * 256 * 2);
    unsigned short* Bp3  = (unsigned short*)alloc((size_t)NCLS_PAD * FDIM * 2);
    float* b1p = (float*)alloc(FDIM * 4);
    float* b2p = (float*)alloc(FDIM * 4);
    float* b3p = (float*)alloc(NCLS_PAD * 4);
    int* rowptr    = (int*)alloc((size_t)(N_NODES + 1) * 4);
    int* esrc      = (int*)alloc((size_t)N_EDGES * 4);
    int* bh        = (int*)alloc((size_t)NBLKB * NBINS * 4);
    int* obh       = (int*)alloc((size_t)NBLKB * NBINS * 4);
    int* bucketbase= (int*)alloc((size_t)(NBINS + 1) * 4);
    unsigned* bsumB = (unsigned*)alloc((size_t)SCANB_NB * 4);
    unsigned* bpack = (unsigned*)alloc((size_t)N_EDGES * 4);

    // prologue: histogram | bf16 convert | weight packs (all independent)
    int proGrid = NBLKB + CVT_NB + PACK_NB;
    k_prologue<<<proGrid, 256, 0, stream>>>(
        dst, bh, (const float4*)x, (ushort4*)xb,
        W1l, W1r, b1, Bp1, b1p, W2l, W2r, b2, Bp2, b2p, Wout, bout, Bp3, b3p);

    // CSR build
    k_scanB1<<<SCANB_NB, 1024, 0, stream>>>(bh, obh, bsumB);
    k_scanB3<<<SCANB_NB, 1024, 0, stream>>>(obh, bsumB, bucketbase);
    k_binwriteB<<<NBLKB, 256, 0, stream>>>(src, dst, obh, bpack);
    k_bucket_csr<<<NBINS, 256, 0, stream>>>(bpack, bucketbase, rowptr, esrc);

    int aggGrid = (N_NODES + 3) / 4;
    int gemmGrid = (N_NODES + 63) / 64;

    // layer 1
    k_aggregate<<<aggGrid, 256, 0, stream>>>(xb, esrc, rowptr, aggn);
    k_gemm_layer<<<gemmGrid, 256, 0, stream>>>(aggn, xb, Bp1, b1p, h1);
    // layer 2 + head
    k_aggregate<<<aggGrid, 256, 0, stream>>>(h1, esrc, rowptr, aggn);
    k_gemm_final<<<gemmGrid, 256, 0, stream>>>(aggn, h1, Bp2, b2p, Bp3, b3p, (float*)d_out);
}